// Round 1
// baseline (530.169 us; speedup 1.0000x reference)
//
#include <hip/hip_runtime.h>
#include <math.h>

#define DEV __device__ __forceinline__

typedef unsigned short u16;
typedef __attribute__((ext_vector_type(8))) short s16x8;   // 8 bf16 (4 VGPRs) MFMA operand
typedef __attribute__((ext_vector_type(4))) float f32x4;   // MFMA accumulator

static constexpr int SEQ = 2048;
static constexpr int DIM = 1024;
static constexpr int HEADS = 16;
static constexpr int HD = 64;

DEV u16 f2bf(float f) {           // round-to-nearest-even fp32 -> bf16 bits
  unsigned u = __float_as_uint(f);
  u = u + 0x7FFFu + ((u >> 16) & 1u);
  return (u16)(u >> 16);
}
DEV float bf2f(u16 b) { return __uint_as_float(((unsigned)b) << 16); }

DEV float gelu_exact(float x) { return 0.5f * x * (1.0f + erff(x * 0.70710678118654752f)); }

// ---------------- LayerNorm over rows of [SEQ][DIM] ----------------
template<bool OUT_BF16>
__global__ __launch_bounds__(256) void ln_rows(const float* __restrict__ in,
                                               const float* __restrict__ gamma,
                                               void* __restrict__ outp) {
  int row = blockIdx.x;
  const float* x = in + (size_t)row * DIM;
  float v[4];
  float s = 0.f;
#pragma unroll
  for (int e = 0; e < 4; ++e) { v[e] = x[threadIdx.x + 256 * e]; s += v[e]; }
  __shared__ float red[8];
  int lane = threadIdx.x & 63, wid = threadIdx.x >> 6;
#pragma unroll
  for (int off = 32; off; off >>= 1) s += __shfl_xor(s, off);
  if (lane == 0) red[wid] = s;
  __syncthreads();
  float mean = (red[0] + red[1] + red[2] + red[3]) * (1.0f / DIM);
  float vs = 0.f;
#pragma unroll
  for (int e = 0; e < 4; ++e) { float d = v[e] - mean; vs += d * d; }
#pragma unroll
  for (int off = 32; off; off >>= 1) vs += __shfl_xor(vs, off);
  __syncthreads();              // everyone done reading red[] for mean
  if (lane == 0) red[wid] = vs;
  __syncthreads();
  float var = (red[0] + red[1] + red[2] + red[3]) * (1.0f / DIM);
  float rstd = rsqrtf(var + 1e-5f);
#pragma unroll
  for (int e = 0; e < 4; ++e) {
    int c = threadIdx.x + 256 * e;
    float o = (v[e] - mean) * rstd * gamma[c];
    if (OUT_BF16) ((u16*)outp)[(size_t)row * DIM + c] = f2bf(o);
    else          ((float*)outp)[(size_t)row * DIM + c] = o;
  }
}

// ------------- fp32 [R][C] -> bf16 [C][R] (weights pre-transpose) -------------
__global__ __launch_bounds__(256) void transpose_convert(const float* __restrict__ in,
                                                         u16* __restrict__ outp,
                                                         int R, int C) {
  __shared__ float tile[64][65];
  int c0 = blockIdx.x * 64, r0 = blockIdx.y * 64;
  int tx = threadIdx.x & 63;
  int ty = threadIdx.x >> 6;
  for (int rr = ty; rr < 64; rr += 4)
    tile[rr][tx] = in[(size_t)(r0 + rr) * C + c0 + tx];
  __syncthreads();
  for (int rr = ty; rr < 64; rr += 4)
    outp[(size_t)(c0 + rr) * R + r0 + tx] = f2bf(tile[tx][rr]);
}

// ------------- C[M][N] = A[M][K](bf16) @ Bt[N][K](bf16)^T, out bf16 or f32 -------------
template<bool OUT_F32>
__global__ __launch_bounds__(256) void gemm_bf16(const u16* __restrict__ A,
                                                 const u16* __restrict__ Bt,
                                                 void* __restrict__ Cout,
                                                 int M, int Nn, int K, float scale) {
  __shared__ __align__(16) u16 As[64][40];
  __shared__ __align__(16) u16 Bs[64][40];
  int n0 = blockIdx.x * 64, m0 = blockIdx.y * 64;
  int tid = threadIdx.x, lane = tid & 63, wid = tid >> 6;
  int l15 = lane & 15, lhi = lane >> 4;
  f32x4 acc[4];
#pragma unroll
  for (int c = 0; c < 4; ++c) acc[c] = f32x4{0.f, 0.f, 0.f, 0.f};
  int sr = tid >> 2, sc = (tid & 3) * 8;
  for (int k0 = 0; k0 < K; k0 += 32) {
    __syncthreads();
    *(s16x8*)&As[sr][sc] = *(const s16x8*)(A + (size_t)(m0 + sr) * K + k0 + sc);
    *(s16x8*)&Bs[sr][sc] = *(const s16x8*)(Bt + (size_t)(n0 + sr) * K + k0 + sc);
    __syncthreads();
    s16x8 a = *(const s16x8*)&As[wid * 16 + l15][lhi * 8];
#pragma unroll
    for (int c = 0; c < 4; ++c) {
      s16x8 b = *(const s16x8*)&Bs[c * 16 + l15][lhi * 8];
      acc[c] = __builtin_amdgcn_mfma_f32_16x16x32_bf16(a, b, acc[c], 0, 0, 0);
    }
  }
  int orow = m0 + wid * 16 + lhi * 4;
  int ocol = n0 + l15;
#pragma unroll
  for (int c = 0; c < 4; ++c)
#pragma unroll
    for (int r = 0; r < 4; ++r) {
      float vv = acc[c][r] * scale;
      size_t idx = (size_t)(orow + r) * Nn + ocol + c * 16;
      if (OUT_F32) ((float*)Cout)[idx] = vv;
      else         ((u16*)Cout)[idx] = f2bf(vv);
    }
}

// ------------- attention pass A: per-row softmax stats m,l -------------
__global__ __launch_bounds__(256) void attn_pass_a(const u16* __restrict__ Q,
                                                   const u16* __restrict__ Kmat,
                                                   float* __restrict__ mbuf,
                                                   float* __restrict__ lbuf) {
  int rb = blockIdx.x, h = blockIdx.y;
  int tid = threadIdx.x, lane = tid & 63, wid = tid >> 6;
  int l15 = lane & 15, lhi = lane >> 4;
  int i0 = rb * 64 + wid * 16;
  __shared__ __align__(16) u16 Kt[32][72];
  s16x8 qf0, qf1;
  {
    const u16* qrow = Q + (size_t)(i0 + l15) * DIM + h * HD;
    qf0 = *(const s16x8*)(qrow + lhi * 8);
    qf1 = *(const s16x8*)(qrow + 32 + lhi * 8);
  }
  const float NEGB = -3.0e38f;
  float mrun[4], lrun[4];
  int rowi[4];
#pragma unroll
  for (int r = 0; r < 4; ++r) { mrun[r] = NEGB; lrun[r] = 0.f; rowi[r] = i0 + lhi * 4 + r; }
  int nchunks = rb * 2 + 2;
  int kr = tid >> 3, kc = (tid & 7) * 8;
  for (int jc = 0; jc < nchunks; ++jc) {
    int j0 = jc * 32;
    __syncthreads();
    *(s16x8*)&Kt[kr][kc] = *(const s16x8*)(Kmat + (size_t)(j0 + kr) * DIM + h * HD + kc);
    __syncthreads();
    f32x4 s0 = f32x4{0.f, 0.f, 0.f, 0.f}, s1 = f32x4{0.f, 0.f, 0.f, 0.f};
    {
      s16x8 k00 = *(const s16x8*)&Kt[l15][lhi * 8];
      s16x8 k01 = *(const s16x8*)&Kt[l15][32 + lhi * 8];
      s0 = __builtin_amdgcn_mfma_f32_16x16x32_bf16(qf0, k00, s0, 0, 0, 0);
      s0 = __builtin_amdgcn_mfma_f32_16x16x32_bf16(qf1, k01, s0, 0, 0, 0);
      s16x8 k10 = *(const s16x8*)&Kt[16 + l15][lhi * 8];
      s16x8 k11 = *(const s16x8*)&Kt[16 + l15][32 + lhi * 8];
      s1 = __builtin_amdgcn_mfma_f32_16x16x32_bf16(qf0, k10, s1, 0, 0, 0);
      s1 = __builtin_amdgcn_mfma_f32_16x16x32_bf16(qf1, k11, s1, 0, 0, 0);
    }
    int jcol0 = j0 + l15, jcol1 = j0 + 16 + l15;
#pragma unroll
    for (int r = 0; r < 4; ++r) {
      float v0 = (jcol0 <= rowi[r]) ? s0[r] : NEGB;
      float v1 = (jcol1 <= rowi[r]) ? s1[r] : NEGB;
      float vm = fmaxf(v0, v1);
#pragma unroll
      for (int off = 1; off < 16; off <<= 1) vm = fmaxf(vm, __shfl_xor(vm, off));
      float mnew = fmaxf(mrun[r], vm);
      if (mnew > -1.0e38f) {
        float e0 = (v0 > -1.0e38f) ? __expf(v0 - mnew) : 0.f;
        float e1 = (v1 > -1.0e38f) ? __expf(v1 - mnew) : 0.f;
        float es = e0 + e1;
#pragma unroll
        for (int off = 1; off < 16; off <<= 1) es += __shfl_xor(es, off);
        float sc = (mrun[r] > -1.0e38f) ? __expf(mrun[r] - mnew) : 0.f;
        lrun[r] = lrun[r] * sc + es;
        mrun[r] = mnew;
      }
    }
  }
  if (l15 == 0) {
#pragma unroll
    for (int r = 0; r < 4; ++r) {
      mbuf[(size_t)h * SEQ + rowi[r]] = mrun[r];
      lbuf[(size_t)h * SEQ + rowi[r]] = lrun[r];
    }
  }
}

// ------------- attention pass B: P (or adj) times [n,64] operand -------------
// MODE 1: out_attn = P@V (f32) + deg (adj row sums, diag = 1)
// MODE 2: g1 = gelu((adj@h0)/deg + v)        (bf16 out)
// MODE 3: g2 = gelu((adj@h1)/deg + g1)       (bf16 out)
template<int MODE>
__global__ __launch_bounds__(256) void attn_pass_b(
    const u16* __restrict__ Q, const u16* __restrict__ Kmat, const u16* __restrict__ X,
    const float* __restrict__ mbuf, const float* __restrict__ lbuf,
    float* __restrict__ deg, const u16* __restrict__ skip, void* __restrict__ outp) {
  int rb = blockIdx.x, h = blockIdx.y;
  int tid = threadIdx.x, lane = tid & 63, wid = tid >> 6;
  int l15 = lane & 15, lhi = lane >> 4;
  int i0 = rb * 64 + wid * 16;
  __shared__ __align__(16) u16 Kt[32][72];
  __shared__ __align__(16) u16 Xt[64][40];       // X^T tile: [d][j]
  __shared__ __align__(16) u16 Pb[4][16][40];    // per-wave P strip [16 rows][32 cols]
  s16x8 qf0, qf1;
  {
    const u16* qrow = Q + (size_t)(i0 + l15) * DIM + h * HD;
    qf0 = *(const s16x8*)(qrow + lhi * 8);
    qf1 = *(const s16x8*)(qrow + 32 + lhi * 8);
  }
  float mr[4], invl[4];
  int rowi[4];
#pragma unroll
  for (int r = 0; r < 4; ++r) {
    rowi[r] = i0 + lhi * 4 + r;
    mr[r] = mbuf[(size_t)h * SEQ + rowi[r]];
    invl[r] = 1.0f / lbuf[(size_t)h * SEQ + rowi[r]];
  }
  f32x4 acc[4];
#pragma unroll
  for (int c = 0; c < 4; ++c) acc[c] = f32x4{0.f, 0.f, 0.f, 0.f};
  float dacc[4] = {0.f, 0.f, 0.f, 0.f};
  int nchunks = rb * 2 + 2;
  int kr = tid >> 3, kc = (tid & 7) * 8;
  for (int jc = 0; jc < nchunks; ++jc) {
    int j0 = jc * 32;
    __syncthreads();
    *(s16x8*)&Kt[kr][kc] = *(const s16x8*)(Kmat + (size_t)(j0 + kr) * DIM + h * HD + kc);
    {
      s16x8 xv = *(const s16x8*)(X + (size_t)(j0 + kr) * DIM + h * HD + kc);
#pragma unroll
      for (int e = 0; e < 8; ++e) Xt[kc + e][kr] = (u16)xv[e];
    }
    __syncthreads();
    f32x4 s0 = f32x4{0.f, 0.f, 0.f, 0.f}, s1 = f32x4{0.f, 0.f, 0.f, 0.f};
    {
      s16x8 k00 = *(const s16x8*)&Kt[l15][lhi * 8];
      s16x8 k01 = *(const s16x8*)&Kt[l15][32 + lhi * 8];
      s0 = __builtin_amdgcn_mfma_f32_16x16x32_bf16(qf0, k00, s0, 0, 0, 0);
      s0 = __builtin_amdgcn_mfma_f32_16x16x32_bf16(qf1, k01, s0, 0, 0, 0);
      s16x8 k10 = *(const s16x8*)&Kt[16 + l15][lhi * 8];
      s16x8 k11 = *(const s16x8*)&Kt[16 + l15][32 + lhi * 8];
      s1 = __builtin_amdgcn_mfma_f32_16x16x32_bf16(qf0, k10, s1, 0, 0, 0);
      s1 = __builtin_amdgcn_mfma_f32_16x16x32_bf16(qf1, k11, s1, 0, 0, 0);
    }
    int jcol0 = j0 + l15, jcol1 = j0 + 16 + l15;
#pragma unroll
    for (int r = 0; r < 4; ++r) {
      float p0 = (jcol0 <= rowi[r]) ? __expf(s0[r] - mr[r]) * invl[r] : 0.f;
      float p1 = (jcol1 <= rowi[r]) ? __expf(s1[r] - mr[r]) * invl[r] : 0.f;
      if (MODE == 1) {
        float t0 = (jcol0 == rowi[r]) ? 1.f : ((p0 < 0.01f) ? 0.f : ((p0 > 0.9f) ? 1.f : p0));
        float t1 = (jcol1 == rowi[r]) ? 1.f : ((p1 < 0.01f) ? 0.f : ((p1 > 0.9f) ? 1.f : p1));
        dacc[r] += t0 + t1;
      } else {
        p0 = (jcol0 == rowi[r]) ? 1.f : ((p0 < 0.01f) ? 0.f : ((p0 > 0.9f) ? 1.f : p0));
        p1 = (jcol1 == rowi[r]) ? 1.f : ((p1 < 0.01f) ? 0.f : ((p1 > 0.9f) ? 1.f : p1));
      }
      Pb[wid][lhi * 4 + r][l15] = f2bf(p0);
      Pb[wid][lhi * 4 + r][16 + l15] = f2bf(p1);
    }
    s16x8 pf = *(const s16x8*)&Pb[wid][l15][lhi * 8];
#pragma unroll
    for (int c = 0; c < 4; ++c) {
      s16x8 xf = *(const s16x8*)&Xt[c * 16 + l15][lhi * 8];
      acc[c] = __builtin_amdgcn_mfma_f32_16x16x32_bf16(pf, xf, acc[c], 0, 0, 0);
    }
  }
  if (MODE == 1) {
#pragma unroll
    for (int r = 0; r < 4; ++r) {
      float dsum = dacc[r];
#pragma unroll
      for (int off = 1; off < 16; off <<= 1) dsum += __shfl_xor(dsum, off);
      if (l15 == 0) deg[(size_t)rowi[r] * HEADS + h] = dsum;
    }
#pragma unroll
    for (int c = 0; c < 4; ++c)
#pragma unroll
      for (int r = 0; r < 4; ++r)
        ((float*)outp)[(size_t)rowi[r] * DIM + h * HD + c * 16 + l15] = acc[c][r];
  } else {
#pragma unroll
    for (int r = 0; r < 4; ++r) {
      float dg = 1.0f / deg[(size_t)rowi[r] * HEADS + h];
#pragma unroll
      for (int c = 0; c < 4; ++c) {
        size_t idx = (size_t)rowi[r] * DIM + h * HD + c * 16 + l15;
        float val = acc[c][r] * dg + bf2f(skip[idx]);
        ((u16*)outp)[idx] = f2bf(gelu_exact(val));
      }
    }
  }
}

// ------------- [32768][64] @ Wt[64][64]^T + bias (+ optional f32 add), bf16 out -------------
template<bool ADD>
__global__ __launch_bounds__(256) void small_gemm(
    const u16* __restrict__ A, const u16* __restrict__ Wt,
    const float* __restrict__ bias, const float* __restrict__ addsrc,
    u16* __restrict__ outp) {
  __shared__ __align__(16) u16 Ws[64][72];
  int tid = threadIdx.x, lane = tid & 63, wid = tid >> 6;
  int l15 = lane & 15, lhi = lane >> 4;
  int m0 = blockIdx.x * 64;
  {
    int r = tid >> 2, cc = (tid & 3) * 8;
    *(s16x8*)&Ws[r][cc] = *(const s16x8*)(Wt + r * 64 + cc);
    *(s16x8*)&Ws[r][cc + 32] = *(const s16x8*)(Wt + r * 64 + cc + 32);
  }
  __syncthreads();
  const u16* arow = A + (size_t)(m0 + wid * 16 + l15) * 64;
  s16x8 a0 = *(const s16x8*)(arow + lhi * 8);
  s16x8 a1 = *(const s16x8*)(arow + 32 + lhi * 8);
  f32x4 acc[4];
#pragma unroll
  for (int c = 0; c < 4; ++c) {
    acc[c] = f32x4{0.f, 0.f, 0.f, 0.f};
    s16x8 b0 = *(const s16x8*)&Ws[c * 16 + l15][lhi * 8];
    s16x8 b1 = *(const s16x8*)&Ws[c * 16 + l15][32 + lhi * 8];
    acc[c] = __builtin_amdgcn_mfma_f32_16x16x32_bf16(a0, b0, acc[c], 0, 0, 0);
    acc[c] = __builtin_amdgcn_mfma_f32_16x16x32_bf16(a1, b1, acc[c], 0, 0, 0);
  }
  int orow = m0 + wid * 16 + lhi * 4;
#pragma unroll
  for (int c = 0; c < 4; ++c)
#pragma unroll
    for (int r = 0; r < 4; ++r) {
      int col = c * 16 + l15;
      size_t idx = (size_t)(orow + r) * 64 + col;
      float v = acc[c][r] + bias[col];
      if (ADD) v += addsrc[idx];
      outp[idx] = f2bf(v);
    }
}

extern "C" void kernel_launch(void* const* d_in, const int* in_sizes, int n_in,
                              void* d_out, int out_size, void* d_ws, size_t ws_size,
                              hipStream_t stream) {
  (void)in_sizes; (void)n_in; (void)out_size; (void)ws_size;
  const float* x       = (const float*)d_in[0];
  const float* gamma_n = (const float*)d_in[1];
  const float* Wq      = (const float*)d_in[2];
  const float* Wk      = (const float*)d_in[3];
  const float* Wv      = (const float*)d_in[4];
  const float* Wout    = (const float*)d_in[5];
  const float* gamma_o = (const float*)d_in[6];
  const float* Wg0     = (const float*)d_in[7];
  const float* bg0     = (const float*)d_in[8];
  const float* Wg1     = (const float*)d_in[9];
  const float* bg1     = (const float*)d_in[10];
  const float* Wlin    = (const float*)d_in[11];
  const float* blin    = (const float*)d_in[12];
  float* out = (float*)d_out;

  char* w = (char*)d_ws;
  size_t off = 0;
  auto alloc = [&](size_t bytes) -> void* {
    void* p = w + off;
    off = (off + bytes + 255) & ~(size_t)255;
    return p;
  };
  u16* xn      = (u16*)alloc((size_t)SEQ * DIM * 2);
  u16* WqT     = (u16*)alloc((size_t)DIM * DIM * 2);
  u16* WkT     = (u16*)alloc((size_t)DIM * DIM * 2);
  u16* WvT     = (u16*)alloc((size_t)DIM * DIM * 2);
  u16* WoT     = (u16*)alloc((size_t)DIM * DIM * 2);
  u16* Wg0T    = (u16*)alloc(64 * 64 * 2);
  u16* Wg1T    = (u16*)alloc(64 * 64 * 2);
  u16* WlinT   = (u16*)alloc(64 * 64 * 2);
  u16* Qb      = (u16*)alloc((size_t)SEQ * DIM * 2);
  u16* Kb      = (u16*)alloc((size_t)SEQ * DIM * 2);
  u16* Vb      = (u16*)alloc((size_t)SEQ * DIM * 2);
  float* mbuf  = (float*)alloc((size_t)HEADS * SEQ * 4);
  float* lbuf  = (float*)alloc((size_t)HEADS * SEQ * 4);
  float* degb  = (float*)alloc((size_t)SEQ * HEADS * 4);
  float* oatt  = (float*)alloc((size_t)SEQ * DIM * 4);
  u16* h0      = (u16*)alloc((size_t)SEQ * DIM * 2);
  u16* g1      = (u16*)alloc((size_t)SEQ * DIM * 2);
  u16* h1      = (u16*)alloc((size_t)SEQ * DIM * 2);
  u16* g2      = (u16*)alloc((size_t)SEQ * DIM * 2);
  u16* Om      = (u16*)alloc((size_t)SEQ * DIM * 2);
  float* Y     = (float*)alloc((size_t)SEQ * DIM * 4);

  // 1) LN(x) -> xn (bf16)
  ln_rows<true><<<SEQ, 256, 0, stream>>>(x, gamma_n, xn);
  // 2) weight transposes fp32->bf16 [N][K]
  transpose_convert<<<dim3(16, 16), 256, 0, stream>>>(Wq, WqT, DIM, DIM);
  transpose_convert<<<dim3(16, 16), 256, 0, stream>>>(Wk, WkT, DIM, DIM);
  transpose_convert<<<dim3(16, 16), 256, 0, stream>>>(Wv, WvT, DIM, DIM);
  transpose_convert<<<dim3(16, 16), 256, 0, stream>>>(Wout, WoT, DIM, DIM);
  transpose_convert<<<dim3(1, 1), 256, 0, stream>>>(Wg0, Wg0T, 64, 64);
  transpose_convert<<<dim3(1, 1), 256, 0, stream>>>(Wg1, Wg1T, 64, 64);
  transpose_convert<<<dim3(1, 1), 256, 0, stream>>>(Wlin, WlinT, 64, 64);
  // 3) Q,K,V projections (Q pre-scaled by d^-0.5 = 0.125)
  gemm_bf16<false><<<dim3(16, 32), 256, 0, stream>>>(xn, WqT, Qb, SEQ, DIM, DIM, 0.125f);
  gemm_bf16<false><<<dim3(16, 32), 256, 0, stream>>>(xn, WkT, Kb, SEQ, DIM, DIM, 1.0f);
  gemm_bf16<false><<<dim3(16, 32), 256, 0, stream>>>(xn, WvT, Vb, SEQ, DIM, DIM, 1.0f);
  // 4) softmax stats
  attn_pass_a<<<dim3(32, 16), 256, 0, stream>>>(Qb, Kb, mbuf, lbuf);
  // 5) out_attn = P@V, deg
  attn_pass_b<1><<<dim3(32, 16), 256, 0, stream>>>(Qb, Kb, Vb, mbuf, lbuf, degb, nullptr, oatt);
  // 6) h0 = V@Wg0 + b0
  small_gemm<false><<<512, 256, 0, stream>>>(Vb, Wg0T, bg0, nullptr, h0);
  // 7) g1 = gelu(adj@h0/deg + v)
  attn_pass_b<2><<<dim3(32, 16), 256, 0, stream>>>(Qb, Kb, h0, mbuf, lbuf, degb, Vb, g1);
  // 8) h1 = g1@Wg1 + b1
  small_gemm<false><<<512, 256, 0, stream>>>(g1, Wg1T, bg1, nullptr, h1);
  // 9) g2 = gelu(adj@h1/deg + g1)
  attn_pass_b<3><<<dim3(32, 16), 256, 0, stream>>>(Qb, Kb, h1, mbuf, lbuf, degb, g1, g2);
  // 10) Om = g2@Wlin + blin + out_attn  (merged [n][h*d] via the [32768][64] view)
  small_gemm<true><<<512, 256, 0, stream>>>(g2, WlinT, blin, oatt, Om);
  // 11) Y = Om @ Wout (f32)
  gemm_bf16<true><<<dim3(16, 32), 256, 0, stream>>>(Om, WoT, Y, SEQ, DIM, DIM, 1.0f);
  // 12) LN(Y) -> out (f32)
  ln_rows<false><<<SEQ, 256, 0, stream>>>(Y, gamma_o, out);
}

// Round 2
// 412.536 us; speedup vs baseline: 1.2851x; 1.2851x over previous
//
#include <hip/hip_runtime.h>
#include <math.h>

#define DEV __device__ __forceinline__

typedef unsigned short u16;
typedef __attribute__((ext_vector_type(8))) short s16x8;   // 8 bf16 (4 VGPRs) MFMA operand
typedef __attribute__((ext_vector_type(4))) float f32x4;   // MFMA accumulator

static constexpr int SEQ = 2048;
static constexpr int DIM = 1024;
static constexpr int HEADS = 16;
static constexpr int HD = 64;
static constexpr int QKVLD = 3072;

DEV u16 f2bf(float f) {           // round-to-nearest-even fp32 -> bf16 bits
  unsigned u = __float_as_uint(f);
  u = u + 0x7FFFu + ((u >> 16) & 1u);
  return (u16)(u >> 16);
}
DEV float bf2f(u16 b) { return __uint_as_float(((unsigned)b) << 16); }

DEV float gelu_exact(float x) { return 0.5f * x * (1.0f + erff(x * 0.70710678118654752f)); }

#define MFMA16(a, b, c) __builtin_amdgcn_mfma_f32_16x16x32_bf16(a, b, c, 0, 0, 0)
#define WAVE_LDS_FENCE() asm volatile("s_waitcnt lgkmcnt(0)" ::: "memory")

// ---------------- LayerNorm over rows of [SEQ][DIM] ----------------
template<bool OUT_BF16>
__global__ __launch_bounds__(256) void ln_rows(const float* __restrict__ in,
                                               const float* __restrict__ gamma,
                                               void* __restrict__ outp) {
  int row = blockIdx.x;
  const float* x = in + (size_t)row * DIM;
  float v[4];
  float s = 0.f;
#pragma unroll
  for (int e = 0; e < 4; ++e) { v[e] = x[threadIdx.x + 256 * e]; s += v[e]; }
  __shared__ float red[8];
  int lane = threadIdx.x & 63, wid = threadIdx.x >> 6;
#pragma unroll
  for (int off = 32; off; off >>= 1) s += __shfl_xor(s, off);
  if (lane == 0) red[wid] = s;
  __syncthreads();
  float mean = (red[0] + red[1] + red[2] + red[3]) * (1.0f / DIM);
  float vs = 0.f;
#pragma unroll
  for (int e = 0; e < 4; ++e) { float d = v[e] - mean; vs += d * d; }
#pragma unroll
  for (int off = 32; off; off >>= 1) vs += __shfl_xor(vs, off);
  __syncthreads();
  if (lane == 0) red[wid] = vs;
  __syncthreads();
  float var = (red[0] + red[1] + red[2] + red[3]) * (1.0f / DIM);
  float rstd = rsqrtf(var + 1e-5f);
#pragma unroll
  for (int e = 0; e < 4; ++e) {
    int c = threadIdx.x + 256 * e;
    float o = (v[e] - mean) * rstd * gamma[c];
    if (OUT_BF16) ((u16*)outp)[(size_t)row * DIM + c] = f2bf(o);
    else          ((float*)outp)[(size_t)row * DIM + c] = o;
  }
}

// ------------- fp32 [R][C] -> bf16 [C][R] (weights pre-transpose) -------------
__global__ __launch_bounds__(256) void transpose_convert(const float* __restrict__ in,
                                                         u16* __restrict__ outp,
                                                         int R, int C) {
  __shared__ float tile[64][65];
  int c0 = blockIdx.x * 64, r0 = blockIdx.y * 64;
  int tx = threadIdx.x & 63;
  int ty = threadIdx.x >> 6;
  for (int rr = ty; rr < 64; rr += 4)
    tile[rr][tx] = in[(size_t)(r0 + rr) * C + c0 + tx];
  __syncthreads();
  for (int rr = ty; rr < 64; rr += 4)
    outp[(size_t)(c0 + rr) * R + r0 + tx] = f2bf(tile[tx][rr]);
}

// ------------- bf16 head-slices [j][h*64+d] (ld) -> [h][64][SEQ] -------------
__global__ __launch_bounds__(256) void transpose_head(const u16* __restrict__ src, int ld,
                                                      u16* __restrict__ dst) {
  int h = blockIdx.y, j0 = blockIdx.x * 64;
  __shared__ u16 t[64][72];
  int r = threadIdx.x >> 3, c8 = (threadIdx.x & 7) * 8;
#pragma unroll
  for (int half = 0; half < 2; ++half) {
    int jr = r + half * 32;
    s16x8 v = *(const s16x8*)(src + (size_t)(j0 + jr) * ld + h * HD + c8);
#pragma unroll
    for (int e = 0; e < 8; ++e) t[c8 + e][jr] = (u16)v[e];
  }
  __syncthreads();
#pragma unroll
  for (int half = 0; half < 2; ++half) {
    int d = r + half * 32;
    s16x8 v = *(const s16x8*)&t[d][c8];
    *(s16x8*)(dst + ((size_t)h * HD + d) * SEQ + j0 + c8) = v;
  }
}

// ------------- C[M][N] = A[M][K](bf16) @ Bt[N][K](bf16)^T -------------
// scale applied to cols < Nq is qs, else 1.
template<bool OUT_F32>
__global__ __launch_bounds__(256) void gemm_bf16(const u16* __restrict__ A,
                                                 const u16* __restrict__ Bt,
                                                 void* __restrict__ Cout,
                                                 int Nn, int K, int Nq, float qs) {
  __shared__ __align__(16) u16 As[64][40];
  __shared__ __align__(16) u16 Bs[64][40];
  int n0 = blockIdx.x * 64, m0 = blockIdx.y * 64;
  int tid = threadIdx.x, lane = tid & 63, wid = tid >> 6;
  int l15 = lane & 15, lhi = lane >> 4;
  float scale = (n0 < Nq) ? qs : 1.0f;
  f32x4 acc[4];
#pragma unroll
  for (int c = 0; c < 4; ++c) acc[c] = f32x4{0.f, 0.f, 0.f, 0.f};
  int sr = tid >> 2, sc = (tid & 3) * 8;
  for (int k0 = 0; k0 < K; k0 += 32) {
    __syncthreads();
    *(s16x8*)&As[sr][sc] = *(const s16x8*)(A + (size_t)(m0 + sr) * K + k0 + sc);
    *(s16x8*)&Bs[sr][sc] = *(const s16x8*)(Bt + (size_t)(n0 + sr) * K + k0 + sc);
    __syncthreads();
    s16x8 a = *(const s16x8*)&As[wid * 16 + l15][lhi * 8];
#pragma unroll
    for (int c = 0; c < 4; ++c) {
      s16x8 b = *(const s16x8*)&Bs[c * 16 + l15][lhi * 8];
      acc[c] = MFMA16(a, b, acc[c]);
    }
  }
  int orow = m0 + wid * 16 + lhi * 4;
  int ocol = n0 + l15;
#pragma unroll
  for (int c = 0; c < 4; ++c)
#pragma unroll
    for (int r = 0; r < 4; ++r) {
      float vv = acc[c][r] * scale;
      size_t idx = (size_t)(orow + r) * Nn + ocol + c * 16;
      if (OUT_F32) ((float*)Cout)[idx] = vv;
      else         ((u16*)Cout)[idx] = f2bf(vv);
    }
}

// ------------- rows[32768-view][64] @ Wt[64][64]^T + bias (+f32 add), bf16 out -------------
// A row R at A + (R>>4)*ldo + (R&15)*64 ; output row-major 1024-ld (== R*64)
template<bool ADD>
__global__ __launch_bounds__(256) void small_gemm(
    const u16* __restrict__ A, int ldo, const u16* __restrict__ Wt,
    const float* __restrict__ bias, const float* __restrict__ addsrc,
    u16* __restrict__ outp) {
  __shared__ __align__(16) u16 Ws[64][72];
  int tid = threadIdx.x, lane = tid & 63, wid = tid >> 6;
  int l15 = lane & 15, lhi = lane >> 4;
  int m0 = blockIdx.x * 64;
  {
    int r = tid >> 2, cc = (tid & 3) * 8;
    *(s16x8*)&Ws[r][cc] = *(const s16x8*)(Wt + r * 64 + cc);
    *(s16x8*)&Ws[r][cc + 32] = *(const s16x8*)(Wt + r * 64 + cc + 32);
  }
  __syncthreads();
  int R = m0 + wid * 16 + l15;
  const u16* arow = A + (size_t)(R >> 4) * ldo + (R & 15) * 64;
  s16x8 a0 = *(const s16x8*)(arow + lhi * 8);
  s16x8 a1 = *(const s16x8*)(arow + 32 + lhi * 8);
  f32x4 acc[4];
#pragma unroll
  for (int c = 0; c < 4; ++c) {
    acc[c] = f32x4{0.f, 0.f, 0.f, 0.f};
    s16x8 b0 = *(const s16x8*)&Ws[c * 16 + l15][lhi * 8];
    s16x8 b1 = *(const s16x8*)&Ws[c * 16 + l15][32 + lhi * 8];
    acc[c] = MFMA16(a0, b0, acc[c]);
    acc[c] = MFMA16(a1, b1, acc[c]);
  }
  int orow = m0 + wid * 16 + lhi * 4;
#pragma unroll
  for (int c = 0; c < 4; ++c)
#pragma unroll
    for (int r = 0; r < 4; ++r) {
      int col = c * 16 + l15;
      size_t idx = (size_t)(orow + r) * 64 + col;
      float v = acc[c][r] + bias[col];
      if (ADD) v += addsrc[idx];
      outp[idx] = f2bf(v);
    }
}

// ======================= fused attention: stats + PV + GCN0 + deg =======================
// One wave per (head, 16-q strip). No block barriers. Swapped QK^T: lane holds
// col q = lane&15 fixed; rows j in regs. Strips descend so heavy blocks launch first.
__global__ __launch_bounds__(256) void attn_pv(
    const u16* __restrict__ QKV,            // [2048][3072] bf16 (Q|K|V)
    const u16* __restrict__ Vt,             // [16][64][2048]
    const u16* __restrict__ H0T,            // [16][64][2048]
    float* __restrict__ mbuf, float* __restrict__ lbuf, float* __restrict__ degb,
    float* __restrict__ oatt,               // [2048][1024] f32
    u16* __restrict__ g1) {                 // [2048][1024] bf16
  int wid = threadIdx.x >> 6, lane = threadIdx.x & 63;
  int l15 = lane & 15, lhi = lane >> 4;
  int w = blockIdx.x * 4 + wid;
  int h = w & 15, sidx = w >> 4;
  int strip = 127 - sidx;
  int qbase = strip * 16;
  int q = qbase + l15;

  __shared__ __align__(16) u16 pls[4][16][72];
  __shared__ __align__(16) u16 als[4][16][72];
  u16 (*pbuf)[72] = pls[wid];
  u16 (*abuf)[72] = als[wid];

  const u16* Qh = QKV + (size_t)h * HD;             // Q at col 0
  const u16* Kh = QKV + 1024 + (size_t)h * HD;      // K at col 1024
  const u16* Vrows = QKV + 2048 + (size_t)h * HD;   // V rows (for skip)
  const u16* Vth = Vt + (size_t)h * HD * SEQ;
  const u16* H0h = H0T + (size_t)h * HD * SEQ;

  const u16* qrow = Qh + (size_t)q * QKVLD;
  s16x8 qf0 = *(const s16x8*)(qrow + lhi * 8);
  s16x8 qf1 = *(const s16x8*)(qrow + 32 + lhi * 8);

  int nch = (qbase + 16 + 63) >> 6;
  const float NEGB = -3.0e38f;

  // ---- phase 1: softmax stats (lane-local online) ----
  float mp = NEGB, lp = 0.f;
  for (int c0 = 0; c0 < nch; ++c0) {
    int j0 = c0 * 64;
    float sv[16];
    float vmax = NEGB;
#pragma unroll
    for (int st = 0; st < 4; ++st) {
      int jb = j0 + st * 16;
      const u16* kr = Kh + (size_t)(jb + l15) * QKVLD;
      s16x8 kf0 = *(const s16x8*)(kr + lhi * 8);
      s16x8 kf1 = *(const s16x8*)(kr + 32 + lhi * 8);
      f32x4 s = f32x4{0.f, 0.f, 0.f, 0.f};
      s = MFMA16(kf0, qf0, s);
      s = MFMA16(kf1, qf1, s);
#pragma unroll
      for (int r = 0; r < 4; ++r) {
        int j = jb + lhi * 4 + r;
        float v = (j <= q) ? s[r] : NEGB;
        sv[st * 4 + r] = v;
        vmax = fmaxf(vmax, v);
      }
    }
    float mn = fmaxf(mp, vmax);
    float es = 0.f;
#pragma unroll
    for (int i = 0; i < 16; ++i) es += __expf(sv[i] - mn);
    lp = lp * __expf(mp - mn) + es;
    mp = mn;
  }
  // combine across the 4 lanes sharing this q (lhi groups)
#pragma unroll
  for (int off = 16; off <= 32; off <<= 1) {
    float mo = __shfl_xor(mp, off), lo = __shfl_xor(lp, off);
    float mn = fmaxf(mp, mo);
    lp = lp * __expf(mp - mn) + lo * __expf(mo - mn);
    mp = mn;
  }
  float invl = 1.0f / lp;
  if (lhi == 0) {
    mbuf[(size_t)h * SEQ + q] = mp;
    lbuf[(size_t)h * SEQ + q] = lp;
  }

  // ---- phase 2: P@V, adj@h0, deg ----
  f32x4 pv[4], gc[4];
#pragma unroll
  for (int c = 0; c < 4; ++c) { pv[c] = f32x4{0.f,0.f,0.f,0.f}; gc[c] = f32x4{0.f,0.f,0.f,0.f}; }
  float dacc = 0.f;
  for (int c0 = 0; c0 < nch; ++c0) {
    int j0 = c0 * 64;
#pragma unroll
    for (int st = 0; st < 4; ++st) {
      int jb = j0 + st * 16;
      const u16* kr = Kh + (size_t)(jb + l15) * QKVLD;
      s16x8 kf0 = *(const s16x8*)(kr + lhi * 8);
      s16x8 kf1 = *(const s16x8*)(kr + 32 + lhi * 8);
      f32x4 s = f32x4{0.f, 0.f, 0.f, 0.f};
      s = MFMA16(kf0, qf0, s);
      s = MFMA16(kf1, qf1, s);
      float pr[4], ar[4];
#pragma unroll
      for (int r = 0; r < 4; ++r) {
        int j = jb + lhi * 4 + r;
        float p = (j <= q) ? __expf(s[r] - mp) * invl : 0.f;
        float a = (j == q) ? 1.f : ((p < 0.01f) ? 0.f : ((p > 0.9f) ? 1.f : p));
        dacc += a;
        pr[r] = p; ar[r] = a;
      }
      ushort4 pu; pu.x = f2bf(pr[0]); pu.y = f2bf(pr[1]); pu.z = f2bf(pr[2]); pu.w = f2bf(pr[3]);
      ushort4 au; au.x = f2bf(ar[0]); au.y = f2bf(ar[1]); au.z = f2bf(ar[2]); au.w = f2bf(ar[3]);
      *(ushort4*)&pbuf[l15][st * 16 + lhi * 4] = pu;
      *(ushort4*)&abuf[l15][st * 16 + lhi * 4] = au;
    }
    WAVE_LDS_FENCE();
#pragma unroll
    for (int kk = 0; kk < 2; ++kk) {
      s16x8 bp = *(const s16x8*)&pbuf[l15][kk * 32 + lhi * 8];
      s16x8 ba = *(const s16x8*)&abuf[l15][kk * 32 + lhi * 8];
#pragma unroll
      for (int c2 = 0; c2 < 4; ++c2) {
        s16x8 av = *(const s16x8*)(Vth + (size_t)(c2 * 16 + l15) * SEQ + j0 + kk * 32 + lhi * 8);
        pv[c2] = MFMA16(av, bp, pv[c2]);
        s16x8 ah = *(const s16x8*)(H0h + (size_t)(c2 * 16 + l15) * SEQ + j0 + kk * 32 + lhi * 8);
        gc[c2] = MFMA16(ah, ba, gc[c2]);
      }
    }
    WAVE_LDS_FENCE();
  }
  // deg reduce over lhi
  dacc += __shfl_xor(dacc, 16);
  dacc += __shfl_xor(dacc, 32);
  if (lhi == 0) degb[(size_t)h * SEQ + q] = dacc;
  float dinv = 1.0f / dacc;
  // write oatt (f32) and g1 = gelu(gc/deg + v)
#pragma unroll
  for (int c2 = 0; c2 < 4; ++c2) {
    *(f32x4*)&oatt[(size_t)q * DIM + h * HD + c2 * 16 + lhi * 4] = pv[c2];
    ushort4 vv = *(const ushort4*)(Vrows + (size_t)q * QKVLD + c2 * 16 + lhi * 4);
    ushort4 o;
    o.x = f2bf(gelu_exact(gc[c2][0] * dinv + bf2f(vv.x)));
    o.y = f2bf(gelu_exact(gc[c2][1] * dinv + bf2f(vv.y)));
    o.z = f2bf(gelu_exact(gc[c2][2] * dinv + bf2f(vv.z)));
    o.w = f2bf(gelu_exact(gc[c2][3] * dinv + bf2f(vv.w)));
    *(ushort4*)&g1[(size_t)q * DIM + h * HD + c2 * 16 + lhi * 4] = o;
  }
}

// ======================= GCN layer 1: g2 = gelu(adj@h1/deg + g1) =======================
__global__ __launch_bounds__(256) void attn_gcn1(
    const u16* __restrict__ QKV,
    const u16* __restrict__ H1T,
    const float* __restrict__ mbuf, const float* __restrict__ lbuf,
    const float* __restrict__ degb,
    const u16* __restrict__ g1, u16* __restrict__ g2) {
  int wid = threadIdx.x >> 6, lane = threadIdx.x & 63;
  int l15 = lane & 15, lhi = lane >> 4;
  int w = blockIdx.x * 4 + wid;
  int h = w & 15, sidx = w >> 4;
  int strip = 127 - sidx;
  int qbase = strip * 16;
  int q = qbase + l15;

  __shared__ __align__(16) u16 als[4][16][72];
  u16 (*abuf)[72] = als[wid];

  const u16* Qh = QKV + (size_t)h * HD;
  const u16* Kh = QKV + 1024 + (size_t)h * HD;
  const u16* H1h = H1T + (size_t)h * HD * SEQ;

  const u16* qrow = Qh + (size_t)q * QKVLD;
  s16x8 qf0 = *(const s16x8*)(qrow + lhi * 8);
  s16x8 qf1 = *(const s16x8*)(qrow + 32 + lhi * 8);

  float mp = mbuf[(size_t)h * SEQ + q];
  float invl = 1.0f / lbuf[(size_t)h * SEQ + q];
  float dinv = 1.0f / degb[(size_t)h * SEQ + q];

  int nch = (qbase + 16 + 63) >> 6;
  f32x4 gc[4];
#pragma unroll
  for (int c = 0; c < 4; ++c) gc[c] = f32x4{0.f, 0.f, 0.f, 0.f};
  for (int c0 = 0; c0 < nch; ++c0) {
    int j0 = c0 * 64;
#pragma unroll
    for (int st = 0; st < 4; ++st) {
      int jb = j0 + st * 16;
      const u16* kr = Kh + (size_t)(jb + l15) * QKVLD;
      s16x8 kf0 = *(const s16x8*)(kr + lhi * 8);
      s16x8 kf1 = *(const s16x8*)(kr + 32 + lhi * 8);
      f32x4 s = f32x4{0.f, 0.f, 0.f, 0.f};
      s = MFMA16(kf0, qf0, s);
      s = MFMA16(kf1, qf1, s);
      float ar[4];
#pragma unroll
      for (int r = 0; r < 4; ++r) {
        int j = jb + lhi * 4 + r;
        float p = (j <= q) ? __expf(s[r] - mp) * invl : 0.f;
        ar[r] = (j == q) ? 1.f : ((p < 0.01f) ? 0.f : ((p > 0.9f) ? 1.f : p));
      }
      ushort4 au; au.x = f2bf(ar[0]); au.y = f2bf(ar[1]); au.z = f2bf(ar[2]); au.w = f2bf(ar[3]);
      *(ushort4*)&abuf[l15][st * 16 + lhi * 4] = au;
    }
    WAVE_LDS_FENCE();
#pragma unroll
    for (int kk = 0; kk < 2; ++kk) {
      s16x8 ba = *(const s16x8*)&abuf[l15][kk * 32 + lhi * 8];
#pragma unroll
      for (int c2 = 0; c2 < 4; ++c2) {
        s16x8 ah = *(const s16x8*)(H1h + (size_t)(c2 * 16 + l15) * SEQ + j0 + kk * 32 + lhi * 8);
        gc[c2] = MFMA16(ah, ba, gc[c2]);
      }
    }
    WAVE_LDS_FENCE();
  }
#pragma unroll
  for (int c2 = 0; c2 < 4; ++c2) {
    ushort4 sv = *(const ushort4*)(g1 + (size_t)q * DIM + h * HD + c2 * 16 + lhi * 4);
    ushort4 o;
    o.x = f2bf(gelu_exact(gc[c2][0] * dinv + bf2f(sv.x)));
    o.y = f2bf(gelu_exact(gc[c2][1] * dinv + bf2f(sv.y)));
    o.z = f2bf(gelu_exact(gc[c2][2] * dinv + bf2f(sv.z)));
    o.w = f2bf(gelu_exact(gc[c2][3] * dinv + bf2f(sv.w)));
    *(ushort4*)&g2[(size_t)q * DIM + h * HD + c2 * 16 + lhi * 4] = o;
  }
}

extern "C" void kernel_launch(void* const* d_in, const int* in_sizes, int n_in,
                              void* d_out, int out_size, void* d_ws, size_t ws_size,
                              hipStream_t stream) {
  (void)in_sizes; (void)n_in; (void)out_size; (void)ws_size;
  const float* x       = (const float*)d_in[0];
  const float* gamma_n = (const float*)d_in[1];
  const float* Wq      = (const float*)d_in[2];
  const float* Wk      = (const float*)d_in[3];
  const float* Wv      = (const float*)d_in[4];
  const float* Wout    = (const float*)d_in[5];
  const float* gamma_o = (const float*)d_in[6];
  const float* Wg0     = (const float*)d_in[7];
  const float* bg0     = (const float*)d_in[8];
  const float* Wg1     = (const float*)d_in[9];
  const float* bg1     = (const float*)d_in[10];
  const float* Wlin    = (const float*)d_in[11];
  const float* blin    = (const float*)d_in[12];
  float* out = (float*)d_out;

  char* w = (char*)d_ws;
  size_t off = 0;
  auto alloc = [&](size_t bytes) -> void* {
    void* p = w + off;
    off = (off + bytes + 255) & ~(size_t)255;
    return p;
  };
  u16* xn      = (u16*)alloc((size_t)SEQ * DIM * 2);
  u16* WqkvT   = (u16*)alloc((size_t)3 * DIM * DIM * 2);
  u16* WoT     = (u16*)alloc((size_t)DIM * DIM * 2);
  u16* Wg0T    = (u16*)alloc(64 * 64 * 2);
  u16* Wg1T    = (u16*)alloc(64 * 64 * 2);
  u16* WlinT   = (u16*)alloc(64 * 64 * 2);
  u16* QKV     = (u16*)alloc((size_t)SEQ * QKVLD * 2);   // 12 MB (reused for Y later)
  float* mbuf  = (float*)alloc((size_t)HEADS * SEQ * 4);
  float* lbuf  = (float*)alloc((size_t)HEADS * SEQ * 4);
  float* degb  = (float*)alloc((size_t)HEADS * SEQ * 4);
  float* oatt  = (float*)alloc((size_t)SEQ * DIM * 4);
  u16* h0      = (u16*)alloc((size_t)SEQ * DIM * 2);
  u16* g1      = (u16*)alloc((size_t)SEQ * DIM * 2);
  u16* h1      = (u16*)alloc((size_t)SEQ * DIM * 2);
  u16* g2      = (u16*)alloc((size_t)SEQ * DIM * 2);
  u16* Vt      = (u16*)alloc((size_t)DIM * SEQ * 2);
  u16* H0T     = (u16*)alloc((size_t)DIM * SEQ * 2);
  u16* H1T     = (u16*)alloc((size_t)DIM * SEQ * 2);
  u16* Om      = (u16*)alloc((size_t)SEQ * DIM * 2);
  float* Y     = (float*)QKV;   // alias: QKV dead after attn_gcn1

  // 1) LN(x) -> xn (bf16)
  ln_rows<true><<<SEQ, 256, 0, stream>>>(x, gamma_n, xn);
  // 2) weight transposes fp32->bf16 [N][K]
  transpose_convert<<<dim3(16, 16), 256, 0, stream>>>(Wq, WqkvT, DIM, DIM);
  transpose_convert<<<dim3(16, 16), 256, 0, stream>>>(Wk, WqkvT + (size_t)DIM * DIM, DIM, DIM);
  transpose_convert<<<dim3(16, 16), 256, 0, stream>>>(Wv, WqkvT + (size_t)2 * DIM * DIM, DIM, DIM);
  transpose_convert<<<dim3(16, 16), 256, 0, stream>>>(Wout, WoT, DIM, DIM);
  transpose_convert<<<dim3(1, 1), 256, 0, stream>>>(Wg0, Wg0T, 64, 64);
  transpose_convert<<<dim3(1, 1), 256, 0, stream>>>(Wg1, Wg1T, 64, 64);
  transpose_convert<<<dim3(1, 1), 256, 0, stream>>>(Wlin, WlinT, 64, 64);
  // 3) fused QKV projection (Q cols scaled by 0.125)
  gemm_bf16<false><<<dim3(48, 32), 256, 0, stream>>>(xn, WqkvT, QKV, QKVLD, DIM, 1024, 0.125f);
  // 4) h0 = V@Wg0 + b0  (V rows inside QKV)
  small_gemm<false><<<512, 256, 0, stream>>>(QKV + 2048, QKVLD, Wg0T, bg0, nullptr, h0);
  // 5) transposes for MFMA A-operands
  transpose_head<<<dim3(32, 16), 256, 0, stream>>>(QKV + 2048, QKVLD, Vt);
  transpose_head<<<dim3(32, 16), 256, 0, stream>>>(h0, DIM, H0T);
  // 6) fused attention: stats + P@V + adj@h0 + deg -> oatt, g1, m/l/deg
  attn_pv<<<512, 256, 0, stream>>>(QKV, Vt, H0T, mbuf, lbuf, degb, oatt, g1);
  // 7) h1 = g1@Wg1 + b1
  small_gemm<false><<<512, 256, 0, stream>>>(g1, DIM, Wg1T, bg1, nullptr, h1);
  // 8) h1T
  transpose_head<<<dim3(32, 16), 256, 0, stream>>>(h1, DIM, H1T);
  // 9) g2 = gelu(adj@h1/deg + g1)
  attn_gcn1<<<512, 256, 0, stream>>>(QKV, H1T, mbuf, lbuf, degb, g1, g2);
  // 10) Om = g2@Wlin + blin + oatt
  small_gemm<true><<<512, 256, 0, stream>>>(g2, DIM, WlinT, blin, oatt, Om);
  // 11) Y = Om @ Wout (f32)  [Y aliases QKV]
  gemm_bf16<true><<<dim3(16, 32), 256, 0, stream>>>(Om, WoT, Y, DIM, DIM, 0, 1.0f);
  // 12) LN(Y) -> out (f32)
  ln_rows<false><<<SEQ, 256, 0, stream>>>(Y, gamma_o, out);
}

// Round 3
// 248.745 us; speedup vs baseline: 2.1314x; 1.6585x over previous
//
#include <hip/hip_runtime.h>
#include <math.h>

#define DEV __device__ __forceinline__

typedef unsigned short u16;
typedef __attribute__((ext_vector_type(8))) short s16x8;   // 8 bf16 (4 VGPRs) MFMA operand
typedef __attribute__((ext_vector_type(4))) float f32x4;   // MFMA accumulator

static constexpr int SEQ = 2048;
static constexpr int DIM = 1024;
static constexpr int HEADS = 16;
static constexpr int HD = 64;
static constexpr int QKVLD = 3072;
static constexpr int TOTCH = 2112;   // sum over strips of nch(strip), nch(s)=s/4+1

DEV u16 f2bf(float f) {           // round-to-nearest-even fp32 -> bf16 bits
  unsigned u = __float_as_uint(f);
  u = u + 0x7FFFu + ((u >> 16) & 1u);
  return (u16)(u >> 16);
}
DEV float bf2f(u16 b) { return __uint_as_float(((unsigned)b) << 16); }

DEV float gelu_exact(float x) { return 0.5f * x * (1.0f + erff(x * 0.70710678118654752f)); }

DEV int cumch(int s) { int a = s >> 2, b = s & 3; return s + 2 * a * (a - 1) + a * b; }

#define MFMA16(a, b, c) __builtin_amdgcn_mfma_f32_16x16x32_bf16(a, b, c, 0, 0, 0)
#define WAVE_LDS_FENCE() asm volatile("s_waitcnt lgkmcnt(0)" ::: "memory")

// ---------------- LayerNorm over rows of [SEQ][DIM] ----------------
template<bool OUT_BF16>
__global__ __launch_bounds__(256) void ln_rows(const float* __restrict__ in,
                                               const float* __restrict__ gamma,
                                               void* __restrict__ outp) {
  int row = blockIdx.x;
  const float* x = in + (size_t)row * DIM;
  float v[4];
  float s = 0.f;
#pragma unroll
  for (int e = 0; e < 4; ++e) { v[e] = x[threadIdx.x + 256 * e]; s += v[e]; }
  __shared__ float red[8];
  int lane = threadIdx.x & 63, wid = threadIdx.x >> 6;
#pragma unroll
  for (int off = 32; off; off >>= 1) s += __shfl_xor(s, off);
  if (lane == 0) red[wid] = s;
  __syncthreads();
  float mean = (red[0] + red[1] + red[2] + red[3]) * (1.0f / DIM);
  float vs = 0.f;
#pragma unroll
  for (int e = 0; e < 4; ++e) { float d = v[e] - mean; vs += d * d; }
#pragma unroll
  for (int off = 32; off; off >>= 1) vs += __shfl_xor(vs, off);
  __syncthreads();
  if (lane == 0) red[wid] = vs;
  __syncthreads();
  float var = (red[0] + red[1] + red[2] + red[3]) * (1.0f / DIM);
  float rstd = rsqrtf(var + 1e-5f);
#pragma unroll
  for (int e = 0; e < 4; ++e) {
    int c = threadIdx.x + 256 * e;
    float o = (v[e] - mean) * rstd * gamma[c];
    if (OUT_BF16) ((u16*)outp)[(size_t)row * DIM + c] = f2bf(o);
    else          ((float*)outp)[(size_t)row * DIM + c] = o;
  }
}

// ------------- fp32 [R][C] -> bf16 [C][R] (weights pre-transpose) -------------
__global__ __launch_bounds__(256) void transpose_convert(const float* __restrict__ in,
                                                         u16* __restrict__ outp,
                                                         int R, int C) {
  __shared__ float tile[64][65];
  int c0 = blockIdx.x * 64, r0 = blockIdx.y * 64;
  int tx = threadIdx.x & 63;
  int ty = threadIdx.x >> 6;
  for (int rr = ty; rr < 64; rr += 4)
    tile[rr][tx] = in[(size_t)(r0 + rr) * C + c0 + tx];
  __syncthreads();
  for (int rr = ty; rr < 64; rr += 4)
    outp[(size_t)(c0 + rr) * R + r0 + tx] = f2bf(tile[tx][rr]);
}

// ------------- pack K rows into per-fragment tiles -------------
// Kp frag(h, jb16, half): lane holds K[(jb16*16+l15)][h*64 + half*32 + lhi*8 .. +8]
__global__ __launch_bounds__(256) void pack_k(const u16* __restrict__ QKV, u16* __restrict__ Kp) {
  int lane = threadIdx.x & 63, wid = threadIdx.x >> 6;
  int l15 = lane & 15, lhi = lane >> 4;
  int h = blockIdx.x & 15, grp = blockIdx.x >> 4;
  int jb = grp * 4 + wid;
  const u16* src = QKV + 1024 + h * HD;
#pragma unroll
  for (int half = 0; half < 2; ++half) {
    s16x8 v = *(const s16x8*)(src + (size_t)(jb * 16 + l15) * QKVLD + half * 32 + lhi * 8);
    *(s16x8*)(Kp + ((size_t)(h * 128 + jb) * 2 + half) * 512 + lane * 8) = v;
  }
}

// ------------- pack a [j][h*64+d] matrix into PV A-operand fragment tiles -------------
// frag(h, jc32, c2): lane holds M[jc*32 + lhi*8 .. +8][h*64 + c2*16 + l15]
__global__ __launch_bounds__(256) void pack_op(const u16* __restrict__ src, int ld, int coloff,
                                               u16* __restrict__ dst) {
  int h = blockIdx.y, j0 = blockIdx.x * 64;
  __shared__ u16 t[64][72];
  int r = threadIdx.x >> 3, c8 = (threadIdx.x & 7) * 8;
#pragma unroll
  for (int half = 0; half < 2; ++half) {
    int jr = r + half * 32;
    s16x8 v = *(const s16x8*)(src + (size_t)(j0 + jr) * ld + coloff + h * HD + c8);
#pragma unroll
    for (int e = 0; e < 8; ++e) t[jr][c8 + e] = (u16)v[e];
  }
  __syncthreads();
  int lane = threadIdx.x & 63, c2 = threadIdx.x >> 6;
  int l15 = lane & 15, lhi = lane >> 4;
#pragma unroll
  for (int jc2 = 0; jc2 < 2; ++jc2) {
    s16x8 v;
#pragma unroll
    for (int e = 0; e < 8; ++e) v[e] = (short)t[jc2 * 32 + lhi * 8 + e][c2 * 16 + l15];
    *(s16x8*)(dst + ((size_t)(h * 64 + (j0 >> 5) + jc2) * 4 + c2) * 512 + lane * 8) = v;
  }
}

// ------------- C[M][N] = A[M][K](bf16) @ Bt[N][K](bf16)^T -------------
template<bool OUT_F32>
__global__ __launch_bounds__(256) void gemm_bf16(const u16* __restrict__ A,
                                                 const u16* __restrict__ Bt,
                                                 void* __restrict__ Cout,
                                                 int Nn, int K, int Nq, float qs) {
  __shared__ __align__(16) u16 As[64][40];
  __shared__ __align__(16) u16 Bs[64][40];
  int n0 = blockIdx.x * 64, m0 = blockIdx.y * 64;
  int tid = threadIdx.x, lane = tid & 63, wid = tid >> 6;
  int l15 = lane & 15, lhi = lane >> 4;
  float scale = (n0 < Nq) ? qs : 1.0f;
  f32x4 acc[4];
#pragma unroll
  for (int c = 0; c < 4; ++c) acc[c] = f32x4{0.f, 0.f, 0.f, 0.f};
  int sr = tid >> 2, sc = (tid & 3) * 8;
  for (int k0 = 0; k0 < K; k0 += 32) {
    __syncthreads();
    *(s16x8*)&As[sr][sc] = *(const s16x8*)(A + (size_t)(m0 + sr) * K + k0 + sc);
    *(s16x8*)&Bs[sr][sc] = *(const s16x8*)(Bt + (size_t)(n0 + sr) * K + k0 + sc);
    __syncthreads();
    s16x8 a = *(const s16x8*)&As[wid * 16 + l15][lhi * 8];
#pragma unroll
    for (int c = 0; c < 4; ++c) {
      s16x8 b = *(const s16x8*)&Bs[c * 16 + l15][lhi * 8];
      acc[c] = MFMA16(a, b, acc[c]);
    }
  }
  int orow = m0 + wid * 16 + lhi * 4;
  int ocol = n0 + l15;
#pragma unroll
  for (int c = 0; c < 4; ++c)
#pragma unroll
    for (int r = 0; r < 4; ++r) {
      float vv = acc[c][r] * scale;
      size_t idx = (size_t)(orow + r) * Nn + ocol + c * 16;
      if (OUT_F32) ((float*)Cout)[idx] = vv;
      else         ((u16*)Cout)[idx] = f2bf(vv);
    }
}

// ------------- rows[(q,h)-view][64] @ Wt[64][64]^T + bias (+f32 add), bf16 out -------------
template<bool ADD>
__global__ __launch_bounds__(256) void small_gemm(
    const u16* __restrict__ A, int ldo, const u16* __restrict__ Wt,
    const float* __restrict__ bias, const float* __restrict__ addsrc,
    u16* __restrict__ outp) {
  __shared__ __align__(16) u16 Ws[64][72];
  int tid = threadIdx.x, lane = tid & 63, wid = tid >> 6;
  int l15 = lane & 15, lhi = lane >> 4;
  int m0 = blockIdx.x * 64;
  {
    int r = tid >> 2, cc = (tid & 3) * 8;
    *(s16x8*)&Ws[r][cc] = *(const s16x8*)(Wt + r * 64 + cc);
    *(s16x8*)&Ws[r][cc + 32] = *(const s16x8*)(Wt + r * 64 + cc + 32);
  }
  __syncthreads();
  int R = m0 + wid * 16 + l15;
  const u16* arow = A + (size_t)(R >> 4) * ldo + (R & 15) * 64;
  s16x8 a0 = *(const s16x8*)(arow + lhi * 8);
  s16x8 a1 = *(const s16x8*)(arow + 32 + lhi * 8);
  f32x4 acc[4];
#pragma unroll
  for (int c = 0; c < 4; ++c) {
    acc[c] = f32x4{0.f, 0.f, 0.f, 0.f};
    s16x8 b0 = *(const s16x8*)&Ws[c * 16 + l15][lhi * 8];
    s16x8 b1 = *(const s16x8*)&Ws[c * 16 + l15][32 + lhi * 8];
    acc[c] = MFMA16(a0, b0, acc[c]);
    acc[c] = MFMA16(a1, b1, acc[c]);
  }
  int orow = m0 + wid * 16 + lhi * 4;
#pragma unroll
  for (int c = 0; c < 4; ++c)
#pragma unroll
    for (int r = 0; r < 4; ++r) {
      int col = c * 16 + l15;
      size_t idx = (size_t)(orow + r) * 64 + col;
      float v = acc[c][r] + bias[col];
      if (ADD) v += addsrc[idx];
      outp[idx] = f2bf(v);
    }
}

// ======================= fused attention: stats + PV + GCN0 + deg (+adj store) ===============
// Two waves per (head, 16-q strip): wave half=0 covers chunks [0,nchA), half=1 [nchA,nch).
// Block = 4 waves = 2 pairs. Partials combined via LDS.
template<bool STORE_ADJ>
__global__ __launch_bounds__(256) void attn_pv(
    const u16* __restrict__ QKV, const u16* __restrict__ Kp,
    const u16* __restrict__ Vp, const u16* __restrict__ H0p,
    float* __restrict__ mbuf, float* __restrict__ lbuf, float* __restrict__ degb,
    float* __restrict__ oatt, u16* __restrict__ g1, u16* __restrict__ adjS) {
  int tid = threadIdx.x, wid = tid >> 6, lane = tid & 63;
  int l15 = lane & 15, lhi = lane >> 4;
  int pairid = blockIdx.x * 2 + (wid >> 1), half = wid & 1;
  int h = pairid & 15, sidx = pairid >> 4;
  int strip = 127 - sidx;
  int qbase = strip * 16, q = qbase + l15;
  int nch = (strip >> 2) + 1;
  int nchA = (nch + 1) >> 1;
  int c_lo = half ? nchA : 0, c_hi = half ? nch : nchA;
  int cumb = cumch(strip);

  __shared__ __align__(16) u16 pls[4][16][72];
  __shared__ __align__(16) u16 als[4][16][72];
  __shared__ float smf[4][16], slf[4][16], sdf[4][16];
  __shared__ float comb[2][8][64][4];
  u16 (*pbuf)[72] = pls[wid];
  u16 (*abuf)[72] = als[wid];

  const u16* qrow = QKV + (size_t)q * QKVLD + h * HD;
  s16x8 qf0 = *(const s16x8*)(qrow + lhi * 8);
  s16x8 qf1 = *(const s16x8*)(qrow + 32 + lhi * 8);
  const u16* KpH = Kp + (size_t)h * 128 * 1024;
  const float NEGB = -3.0e38f;

  // ---- phase 1: softmax stats over this wave's chunk range ----
  float mp = NEGB, lp = 0.f;
  for (int c0 = c_lo; c0 < c_hi; ++c0) {
    int j0 = c0 * 64;
    float sv[16], vmax = NEGB;
#pragma unroll
    for (int st = 0; st < 4; ++st) {
      const u16* kb = KpH + (size_t)((j0 >> 4) + st) * 1024;
      s16x8 kf0 = *(const s16x8*)(kb + lane * 8);
      s16x8 kf1 = *(const s16x8*)(kb + 512 + lane * 8);
      f32x4 s = f32x4{0.f, 0.f, 0.f, 0.f};
      s = MFMA16(kf0, qf0, s);
      s = MFMA16(kf1, qf1, s);
#pragma unroll
      for (int r = 0; r < 4; ++r) {
        int j = j0 + st * 16 + lhi * 4 + r;
        float v = (j <= q) ? s[r] : NEGB;
        sv[st * 4 + r] = v;
        vmax = fmaxf(vmax, v);
      }
    }
    float mn = fmaxf(mp, vmax);
    float es = 0.f;
#pragma unroll
    for (int i = 0; i < 16; ++i) es += __expf(sv[i] - mn);
    lp = lp * __expf(mp - mn) + es;
    mp = mn;
  }
  // reduce across the 4 lhi lanes sharing q
#pragma unroll
  for (int off = 16; off <= 32; off <<= 1) {
    float mo = __shfl_xor(mp, off), lo = __shfl_xor(lp, off);
    float mn = fmaxf(mp, mo);
    lp = lp * __expf(mp - mn) + lo * __expf(mo - mn);
    mp = mn;
  }
  // combine across the wave pair
  if (lhi == 0) { smf[wid][l15] = mp; slf[wid][l15] = lp; }
  __syncthreads();
  {
    float mo = smf[wid ^ 1][l15], lo = slf[wid ^ 1][l15];
    float mn = fmaxf(mp, mo);
    lp = lp * __expf(mp - mn) + lo * __expf(mo - mn);
    mp = mn;
  }
  if (half == 0 && lhi == 0) {
    mbuf[(size_t)h * SEQ + q] = mp;
    lbuf[(size_t)h * SEQ + q] = lp;
  }
  float invl = 1.0f / lp;

  // ---- phase 2: P@V, adj@h0, deg over this wave's chunk range ----
  f32x4 pv[4], gc[4];
#pragma unroll
  for (int c = 0; c < 4; ++c) { pv[c] = f32x4{0.f,0.f,0.f,0.f}; gc[c] = f32x4{0.f,0.f,0.f,0.f}; }
  float dacc = 0.f;
  for (int c0 = c_lo; c0 < c_hi; ++c0) {
    int j0 = c0 * 64;
#pragma unroll
    for (int st = 0; st < 4; ++st) {
      const u16* kb = KpH + (size_t)((j0 >> 4) + st) * 1024;
      s16x8 kf0 = *(const s16x8*)(kb + lane * 8);
      s16x8 kf1 = *(const s16x8*)(kb + 512 + lane * 8);
      f32x4 s = f32x4{0.f, 0.f, 0.f, 0.f};
      s = MFMA16(kf0, qf0, s);
      s = MFMA16(kf1, qf1, s);
      float pr[4], ar[4];
#pragma unroll
      for (int r = 0; r < 4; ++r) {
        int j = j0 + st * 16 + lhi * 4 + r;
        float p = (j <= q) ? __expf(s[r] - mp) * invl : 0.f;
        float a = (j == q) ? 1.f : ((p < 0.01f) ? 0.f : ((p > 0.9f) ? 1.f : p));
        dacc += a;
        pr[r] = p; ar[r] = a;
      }
      ushort4 pu; pu.x = f2bf(pr[0]); pu.y = f2bf(pr[1]); pu.z = f2bf(pr[2]); pu.w = f2bf(pr[3]);
      ushort4 au; au.x = f2bf(ar[0]); au.y = f2bf(ar[1]); au.z = f2bf(ar[2]); au.w = f2bf(ar[3]);
      *(ushort4*)&pbuf[l15][st * 16 + lhi * 4] = pu;
      *(ushort4*)&abuf[l15][st * 16 + lhi * 4] = au;
    }
    WAVE_LDS_FENCE();
#pragma unroll
    for (int kk = 0; kk < 2; ++kk) {
      s16x8 bp = *(const s16x8*)&pbuf[l15][kk * 32 + lhi * 8];
      s16x8 ba = *(const s16x8*)&abuf[l15][kk * 32 + lhi * 8];
      if (STORE_ADJ)
        *(s16x8*)(adjS + ((size_t)(h * TOTCH + cumb + c0) * 2 + kk) * 512 + lane * 8) = ba;
      int jc = (j0 >> 5) + kk;
      const u16* vb = Vp + (size_t)(h * 64 + jc) * 4 * 512;
      const u16* hb = H0p + (size_t)(h * 64 + jc) * 4 * 512;
#pragma unroll
      for (int c2 = 0; c2 < 4; ++c2) {
        s16x8 av = *(const s16x8*)(vb + c2 * 512 + lane * 8);
        pv[c2] = MFMA16(av, bp, pv[c2]);
        s16x8 ah = *(const s16x8*)(hb + c2 * 512 + lane * 8);
        gc[c2] = MFMA16(ah, ba, gc[c2]);
      }
    }
  }
  // deg partial: reduce lhi, stash
  dacc += __shfl_xor(dacc, 16);
  dacc += __shfl_xor(dacc, 32);
  if (lhi == 0) sdf[wid][l15] = dacc;
  // odd wave publishes accumulator partials
  if (half == 1) {
    int pr2 = wid >> 1;
#pragma unroll
    for (int c2 = 0; c2 < 4; ++c2) {
      *(f32x4*)&comb[pr2][c2][lane][0] = pv[c2];
      *(f32x4*)&comb[pr2][4 + c2][lane][0] = gc[c2];
    }
  }
  __syncthreads();
  if (half == 0) {
    int pr2 = wid >> 1;
    float dtot = sdf[wid][l15] + sdf[wid ^ 1][l15];
    if (lhi == 0) degb[(size_t)h * SEQ + q] = dtot;
    float dinv = 1.0f / dtot;
    const u16* Vrows = QKV + 2048 + (size_t)h * HD;
#pragma unroll
    for (int c2 = 0; c2 < 4; ++c2) {
      f32x4 pvt = pv[c2] + *(const f32x4*)&comb[pr2][c2][lane][0];
      f32x4 gct = gc[c2] + *(const f32x4*)&comb[pr2][4 + c2][lane][0];
      *(f32x4*)&oatt[(size_t)q * DIM + h * HD + c2 * 16 + lhi * 4] = pvt;
      ushort4 vv = *(const ushort4*)(Vrows + (size_t)q * QKVLD + c2 * 16 + lhi * 4);
      ushort4 o;
      o.x = f2bf(gelu_exact(gct[0] * dinv + bf2f(vv.x)));
      o.y = f2bf(gelu_exact(gct[1] * dinv + bf2f(vv.y)));
      o.z = f2bf(gelu_exact(gct[2] * dinv + bf2f(vv.z)));
      o.w = f2bf(gelu_exact(gct[3] * dinv + bf2f(vv.w)));
      *(ushort4*)&g1[(size_t)q * DIM + h * HD + c2 * 16 + lhi * 4] = o;
    }
  }
}

// ======================= GCN layer 1: g2 = gelu(adj@h1/deg + g1) =======================
template<bool READ_ADJ>
__global__ __launch_bounds__(256) void attn_gcn1(
    const u16* __restrict__ QKV, const u16* __restrict__ Kp,
    const u16* __restrict__ H1p, const u16* __restrict__ adjS,
    const float* __restrict__ mbuf, const float* __restrict__ lbuf,
    const float* __restrict__ degb,
    const u16* __restrict__ g1, u16* __restrict__ g2) {
  int tid = threadIdx.x, wid = tid >> 6, lane = tid & 63;
  int l15 = lane & 15, lhi = lane >> 4;
  int pairid = blockIdx.x * 2 + (wid >> 1), half = wid & 1;
  int h = pairid & 15, sidx = pairid >> 4;
  int strip = 127 - sidx;
  int qbase = strip * 16, q = qbase + l15;
  int nch = (strip >> 2) + 1;
  int nchA = (nch + 1) >> 1;
  int c_lo = half ? nchA : 0, c_hi = half ? nch : nchA;
  int cumb = cumch(strip);

  __shared__ float comb[2][4][64][4];

  f32x4 gc[4];
#pragma unroll
  for (int c = 0; c < 4; ++c) gc[c] = f32x4{0.f, 0.f, 0.f, 0.f};

  if constexpr (READ_ADJ) {
    for (int c0 = c_lo; c0 < c_hi; ++c0) {
      int j0 = c0 * 64;
#pragma unroll
      for (int kk = 0; kk < 2; ++kk) {
        s16x8 ba = *(const s16x8*)(adjS + ((size_t)(h * TOTCH + cumb + c0) * 2 + kk) * 512 + lane * 8);
        int jc = (j0 >> 5) + kk;
        const u16* hb = H1p + (size_t)(h * 64 + jc) * 4 * 512;
#pragma unroll
        for (int c2 = 0; c2 < 4; ++c2) {
          s16x8 ah = *(const s16x8*)(hb + c2 * 512 + lane * 8);
          gc[c2] = MFMA16(ah, ba, gc[c2]);
        }
      }
    }
  } else {
    __shared__ __align__(16) u16 als[4][16][72];
    u16 (*abuf)[72] = als[wid];
    const u16* qrow = QKV + (size_t)q * QKVLD + h * HD;
    s16x8 qf0 = *(const s16x8*)(qrow + lhi * 8);
    s16x8 qf1 = *(const s16x8*)(qrow + 32 + lhi * 8);
    const u16* KpH = Kp + (size_t)h * 128 * 1024;
    float mp = mbuf[(size_t)h * SEQ + q];
    float invl = 1.0f / lbuf[(size_t)h * SEQ + q];
    for (int c0 = c_lo; c0 < c_hi; ++c0) {
      int j0 = c0 * 64;
#pragma unroll
      for (int st = 0; st < 4; ++st) {
        const u16* kb = KpH + (size_t)((j0 >> 4) + st) * 1024;
        s16x8 kf0 = *(const s16x8*)(kb + lane * 8);
        s16x8 kf1 = *(const s16x8*)(kb + 512 + lane * 8);
        f32x4 s = f32x4{0.f, 0.f, 0.f, 0.f};
        s = MFMA16(kf0, qf0, s);
        s = MFMA16(kf1, qf1, s);
        float ar[4];
#pragma unroll
        for (int r = 0; r < 4; ++r) {
          int j = j0 + st * 16 + lhi * 4 + r;
          float p = (j <= q) ? __expf(s[r] - mp) * invl : 0.f;
          ar[r] = (j == q) ? 1.f : ((p < 0.01f) ? 0.f : ((p > 0.9f) ? 1.f : p));
        }
        ushort4 au; au.x = f2bf(ar[0]); au.y = f2bf(ar[1]); au.z = f2bf(ar[2]); au.w = f2bf(ar[3]);
        *(ushort4*)&abuf[l15][st * 16 + lhi * 4] = au;
      }
      WAVE_LDS_FENCE();
#pragma unroll
      for (int kk = 0; kk < 2; ++kk) {
        s16x8 ba = *(const s16x8*)&abuf[l15][kk * 32 + lhi * 8];
        int jc = (j0 >> 5) + kk;
        const u16* hb = H1p + (size_t)(h * 64 + jc) * 4 * 512;
#pragma unroll
        for (int c2 = 0; c2 < 4; ++c2) {
          s16x8 ah = *(const s16x8*)(hb + c2 * 512 + lane * 8);
          gc[c2] = MFMA16(ah, ba, gc[c2]);
        }
      }
    }
  }

  if (half == 1) {
    int pr2 = wid >> 1;
#pragma unroll
    for (int c2 = 0; c2 < 4; ++c2) *(f32x4*)&comb[pr2][c2][lane][0] = gc[c2];
  }
  __syncthreads();
  if (half == 0) {
    int pr2 = wid >> 1;
    float dinv = 1.0f / degb[(size_t)h * SEQ + q];
#pragma unroll
    for (int c2 = 0; c2 < 4; ++c2) {
      f32x4 gct = gc[c2] + *(const f32x4*)&comb[pr2][c2][lane][0];
      ushort4 sv = *(const ushort4*)(g1 + (size_t)q * DIM + h * HD + c2 * 16 + lhi * 4);
      ushort4 o;
      o.x = f2bf(gelu_exact(gct[0] * dinv + bf2f(sv.x)));
      o.y = f2bf(gelu_exact(gct[1] * dinv + bf2f(sv.y)));
      o.z = f2bf(gelu_exact(gct[2] * dinv + bf2f(sv.z)));
      o.w = f2bf(gelu_exact(gct[3] * dinv + bf2f(sv.w)));
      *(ushort4*)&g2[(size_t)q * DIM + h * HD + c2 * 16 + lhi * 4] = o;
    }
  }
}

extern "C" void kernel_launch(void* const* d_in, const int* in_sizes, int n_in,
                              void* d_out, int out_size, void* d_ws, size_t ws_size,
                              hipStream_t stream) {
  (void)in_sizes; (void)n_in; (void)out_size;
  const float* x       = (const float*)d_in[0];
  const float* gamma_n = (const float*)d_in[1];
  const float* Wq      = (const float*)d_in[2];
  const float* Wk      = (const float*)d_in[3];
  const float* Wv      = (const float*)d_in[4];
  const float* Wout    = (const float*)d_in[5];
  const float* gamma_o = (const float*)d_in[6];
  const float* Wg0     = (const float*)d_in[7];
  const float* bg0     = (const float*)d_in[8];
  const float* Wg1     = (const float*)d_in[9];
  const float* bg1     = (const float*)d_in[10];
  const float* Wlin    = (const float*)d_in[11];
  const float* blin    = (const float*)d_in[12];
  float* out = (float*)d_out;

  char* w = (char*)d_ws;
  size_t off = 0;
  auto alloc = [&](size_t bytes) -> void* {
    void* p = w + off;
    off = (off + bytes + 255) & ~(size_t)255;
    return p;
  };
  u16* xn      = (u16*)alloc((size_t)SEQ * DIM * 2);
  u16* WqkvT   = (u16*)alloc((size_t)3 * DIM * DIM * 2);
  u16* WoT     = (u16*)alloc((size_t)DIM * DIM * 2);
  u16* Wg0T    = (u16*)alloc(64 * 64 * 2);
  u16* Wg1T    = (u16*)alloc(64 * 64 * 2);
  u16* WlinT   = (u16*)alloc(64 * 64 * 2);
  u16* QKV     = (u16*)alloc((size_t)SEQ * QKVLD * 2);
  float* mbuf  = (float*)alloc((size_t)HEADS * SEQ * 4);
  float* lbuf  = (float*)alloc((size_t)HEADS * SEQ * 4);
  float* degb  = (float*)alloc((size_t)HEADS * SEQ * 4);
  float* oatt  = (float*)alloc((size_t)SEQ * DIM * 4);
  u16* h0      = (u16*)alloc((size_t)SEQ * DIM * 2);
  u16* g1      = (u16*)alloc((size_t)SEQ * DIM * 2);
  u16* h1      = (u16*)alloc((size_t)SEQ * DIM * 2);
  u16* g2      = (u16*)alloc((size_t)SEQ * DIM * 2);
  u16* Kp      = (u16*)alloc((size_t)HEADS * 128 * 1024 * 2);
  u16* Vp      = (u16*)alloc((size_t)HEADS * 64 * 4 * 512 * 2);
  u16* H0p     = (u16*)alloc((size_t)HEADS * 64 * 4 * 512 * 2);
  u16* H1p     = (u16*)alloc((size_t)HEADS * 64 * 4 * 512 * 2);
  u16* Om      = (u16*)alloc((size_t)SEQ * DIM * 2);
  float* Y     = (float*)QKV;   // alias: QKV dead after attn_gcn1

  size_t adj_bytes = (size_t)HEADS * TOTCH * 2 * 512 * 2;   // ~66 MB, causal-packed
  bool use_adj = (off + adj_bytes) <= ws_size;
  u16* adjS = use_adj ? (u16*)alloc(adj_bytes) : nullptr;

  // 1) LN(x) -> xn (bf16)
  ln_rows<true><<<SEQ, 256, 0, stream>>>(x, gamma_n, xn);
  // 2) weight transposes fp32->bf16 [N][K]
  transpose_convert<<<dim3(16, 16), 256, 0, stream>>>(Wq, WqkvT, DIM, DIM);
  transpose_convert<<<dim3(16, 16), 256, 0, stream>>>(Wk, WqkvT + (size_t)DIM * DIM, DIM, DIM);
  transpose_convert<<<dim3(16, 16), 256, 0, stream>>>(Wv, WqkvT + (size_t)2 * DIM * DIM, DIM, DIM);
  transpose_convert<<<dim3(16, 16), 256, 0, stream>>>(Wout, WoT, DIM, DIM);
  transpose_convert<<<dim3(1, 1), 256, 0, stream>>>(Wg0, Wg0T, 64, 64);
  transpose_convert<<<dim3(1, 1), 256, 0, stream>>>(Wg1, Wg1T, 64, 64);
  transpose_convert<<<dim3(1, 1), 256, 0, stream>>>(Wlin, WlinT, 64, 64);
  // 3) fused QKV projection (Q cols scaled by 0.125)
  gemm_bf16<false><<<dim3(48, 32), 256, 0, stream>>>(xn, WqkvT, QKV, QKVLD, DIM, 1024, 0.125f);
  // 4) pack K fragments
  pack_k<<<512, 256, 0, stream>>>(QKV, Kp);
  // 5) h0 = V@Wg0 + b0
  small_gemm<false><<<512, 256, 0, stream>>>(QKV + 2048, QKVLD, Wg0T, bg0, nullptr, h0);
  // 6) pack V, h0 fragments
  pack_op<<<dim3(32, 16), 256, 0, stream>>>(QKV, QKVLD, 2048, Vp);
  pack_op<<<dim3(32, 16), 256, 0, stream>>>(h0, DIM, 0, H0p);
  // 7) fused attention (stats + P@V + adj@h0 + deg [+ adj store])
  if (use_adj)
    attn_pv<true><<<1024, 256, 0, stream>>>(QKV, Kp, Vp, H0p, mbuf, lbuf, degb, oatt, g1, adjS);
  else
    attn_pv<false><<<1024, 256, 0, stream>>>(QKV, Kp, Vp, H0p, mbuf, lbuf, degb, oatt, g1, nullptr);
  // 8) h1 = g1@Wg1 + b1
  small_gemm<false><<<512, 256, 0, stream>>>(g1, DIM, Wg1T, bg1, nullptr, h1);
  // 9) pack h1 fragments
  pack_op<<<dim3(32, 16), 256, 0, stream>>>(h1, DIM, 0, H1p);
  // 10) g2 = gelu(adj@h1/deg + g1)
  if (use_adj)
    attn_gcn1<true><<<1024, 256, 0, stream>>>(QKV, Kp, H1p, adjS, mbuf, lbuf, degb, g1, g2);
  else
    attn_gcn1<false><<<1024, 256, 0, stream>>>(QKV, Kp, H1p, nullptr, mbuf, lbuf, degb, g1, g2);
  // 11) Om = g2@Wlin + blin + oatt
  small_gemm<true><<<512, 256, 0, stream>>>(g2, DIM, WlinT, blin, oatt, Om);
  // 12) Y = Om @ Wout (f32)  [Y aliases QKV]
  gemm_bf16<true><<<dim3(16, 32), 256, 0, stream>>>(Om, WoT, Y, DIM, DIM, 0, 1.0f);
  // 13) LN(Y) -> out (f32)
  ln_rows<false><<<SEQ, 256, 0, stream>>>(Y, gamma_o, out);
}

// Round 4
// 195.036 us; speedup vs baseline: 2.7183x; 1.2754x over previous
//
#include <hip/hip_runtime.h>
#include <math.h>
#include <stdint.h>

#define DEV __device__ __forceinline__

typedef unsigned short u16;
typedef __attribute__((ext_vector_type(8))) short s16x8;   // 8 bf16 (4 VGPRs) MFMA operand
typedef __attribute__((ext_vector_type(4))) float f32x4;   // MFMA accumulator

static constexpr int SEQ = 2048;
static constexpr int DIM = 1024;
static constexpr int HEADS = 16;
static constexpr int HD = 64;
static constexpr int QKVLD = 3072;
static constexpr int TOTCH = 2112;   // sum over strips of nch(strip), nch(s)=s/4+1

DEV u16 f2bf(float f) {           // round-to-nearest-even fp32 -> bf16 bits
  unsigned u = __float_as_uint(f);
  u = u + 0x7FFFu + ((u >> 16) & 1u);
  return (u16)(u >> 16);
}
DEV float bf2f(u16 b) { return __uint_as_float(((unsigned)b) << 16); }

DEV float gelu_exact(float x) { return 0.5f * x * (1.0f + erff(x * 0.70710678118654752f)); }

DEV int cumch(int s) { int a = s >> 2, b = s & 3; return s + 2 * a * (a - 1) + a * b; }

#define MFMA16(a, b, c) __builtin_amdgcn_mfma_f32_16x16x32_bf16(a, b, c, 0, 0, 0)
#define WAVE_LDS_FENCE() asm volatile("s_waitcnt lgkmcnt(0)" ::: "memory")

// async global->LDS, 16B per lane; LDS dest = wave-uniform base + lane*16
DEV void gload_lds16(const u16* g, u16* l) {
  __builtin_amdgcn_global_load_lds(
      (const __attribute__((address_space(1))) unsigned int*)g,
      (__attribute__((address_space(3))) unsigned int*)(unsigned int)(uintptr_t)l,
      16, 0, 0);
}

// ---------------- LayerNorm over rows of [SEQ][DIM] ----------------
template<bool OUT_BF16>
__global__ __launch_bounds__(256) void ln_rows(const float* __restrict__ in,
                                               const float* __restrict__ gamma,
                                               void* __restrict__ outp) {
  int row = blockIdx.x;
  const float* x = in + (size_t)row * DIM;
  float v[4];
  float s = 0.f;
#pragma unroll
  for (int e = 0; e < 4; ++e) { v[e] = x[threadIdx.x + 256 * e]; s += v[e]; }
  __shared__ float red[8];
  int lane = threadIdx.x & 63, wid = threadIdx.x >> 6;
#pragma unroll
  for (int off = 32; off; off >>= 1) s += __shfl_xor(s, off);
  if (lane == 0) red[wid] = s;
  __syncthreads();
  float mean = (red[0] + red[1] + red[2] + red[3]) * (1.0f / DIM);
  float vs = 0.f;
#pragma unroll
  for (int e = 0; e < 4; ++e) { float d = v[e] - mean; vs += d * d; }
#pragma unroll
  for (int off = 32; off; off >>= 1) vs += __shfl_xor(vs, off);
  __syncthreads();
  if (lane == 0) red[wid] = vs;
  __syncthreads();
  float var = (red[0] + red[1] + red[2] + red[3]) * (1.0f / DIM);
  float rstd = rsqrtf(var + 1e-5f);
#pragma unroll
  for (int e = 0; e < 4; ++e) {
    int c = threadIdx.x + 256 * e;
    float o = (v[e] - mean) * rstd * gamma[c];
    if (OUT_BF16) ((u16*)outp)[(size_t)row * DIM + c] = f2bf(o);
    else          ((float*)outp)[(size_t)row * DIM + c] = o;
  }
}

// ------------- fp32 [R][C] -> bf16 [C][R] (weights pre-transpose) -------------
__global__ __launch_bounds__(256) void transpose_convert(const float* __restrict__ in,
                                                         u16* __restrict__ outp,
                                                         int R, int C) {
  __shared__ float tile[64][65];
  int c0 = blockIdx.x * 64, r0 = blockIdx.y * 64;
  int tx = threadIdx.x & 63;
  int ty = threadIdx.x >> 6;
  for (int rr = ty; rr < 64; rr += 4)
    tile[rr][tx] = in[(size_t)(r0 + rr) * C + c0 + tx];
  __syncthreads();
  for (int rr = ty; rr < 64; rr += 4)
    outp[(size_t)(c0 + rr) * R + r0 + tx] = f2bf(tile[tx][rr]);
}

// ------------- pack K rows into per-fragment tiles -------------
__global__ __launch_bounds__(256) void pack_k(const u16* __restrict__ QKV, u16* __restrict__ Kp) {
  int lane = threadIdx.x & 63, wid = threadIdx.x >> 6;
  int l15 = lane & 15, lhi = lane >> 4;
  int h = blockIdx.x & 15, grp = blockIdx.x >> 4;
  int jb = grp * 4 + wid;
  const u16* src = QKV + 1024 + h * HD;
#pragma unroll
  for (int half = 0; half < 2; ++half) {
    s16x8 v = *(const s16x8*)(src + (size_t)(jb * 16 + l15) * QKVLD + half * 32 + lhi * 8);
    *(s16x8*)(Kp + ((size_t)(h * 128 + jb) * 2 + half) * 512 + lane * 8) = v;
  }
}

// ------------- pack a [j][h*64+d] matrix into PV A-operand fragment tiles -------------
__global__ __launch_bounds__(256) void pack_op(const u16* __restrict__ src, int ld, int coloff,
                                               u16* __restrict__ dst) {
  int h = blockIdx.y, j0 = blockIdx.x * 64;
  __shared__ u16 t[64][72];
  int r = threadIdx.x >> 3, c8 = (threadIdx.x & 7) * 8;
#pragma unroll
  for (int half = 0; half < 2; ++half) {
    int jr = r + half * 32;
    s16x8 v = *(const s16x8*)(src + (size_t)(j0 + jr) * ld + coloff + h * HD + c8);
#pragma unroll
    for (int e = 0; e < 8; ++e) t[jr][c8 + e] = (u16)v[e];
  }
  __syncthreads();
  int lane = threadIdx.x & 63, c2 = threadIdx.x >> 6;
  int l15 = lane & 15, lhi = lane >> 4;
#pragma unroll
  for (int jc2 = 0; jc2 < 2; ++jc2) {
    s16x8 v;
#pragma unroll
    for (int e = 0; e < 8; ++e) v[e] = (short)t[jc2 * 32 + lhi * 8 + e][c2 * 16 + l15];
    *(s16x8*)(dst + ((size_t)(h * 64 + (j0 >> 5) + jc2) * 4 + c2) * 512 + lane * 8) = v;
  }
}

// ------------- 64x64-tile GEMM (kept for Wout: 512 blocks) -------------
template<bool OUT_F32>
__global__ __launch_bounds__(256) void gemm_bf16(const u16* __restrict__ A,
                                                 const u16* __restrict__ Bt,
                                                 void* __restrict__ Cout,
                                                 int Nn, int K, int Nq, float qs) {
  __shared__ __align__(16) u16 As[64][40];
  __shared__ __align__(16) u16 Bs[64][40];
  int n0 = blockIdx.x * 64, m0 = blockIdx.y * 64;
  int tid = threadIdx.x, lane = tid & 63, wid = tid >> 6;
  int l15 = lane & 15, lhi = lane >> 4;
  float scale = (n0 < Nq) ? qs : 1.0f;
  f32x4 acc[4];
#pragma unroll
  for (int c = 0; c < 4; ++c) acc[c] = f32x4{0.f, 0.f, 0.f, 0.f};
  int sr = tid >> 2, sc = (tid & 3) * 8;
  for (int k0 = 0; k0 < K; k0 += 32) {
    __syncthreads();
    *(s16x8*)&As[sr][sc] = *(const s16x8*)(A + (size_t)(m0 + sr) * K + k0 + sc);
    *(s16x8*)&Bs[sr][sc] = *(const s16x8*)(Bt + (size_t)(n0 + sr) * K + k0 + sc);
    __syncthreads();
    s16x8 a = *(const s16x8*)&As[wid * 16 + l15][lhi * 8];
#pragma unroll
    for (int c = 0; c < 4; ++c) {
      s16x8 b = *(const s16x8*)&Bs[c * 16 + l15][lhi * 8];
      acc[c] = MFMA16(a, b, acc[c]);
    }
  }
  int orow = m0 + wid * 16 + lhi * 4;
  int ocol = n0 + l15;
#pragma unroll
  for (int c = 0; c < 4; ++c)
#pragma unroll
    for (int r = 0; r < 4; ++r) {
      float vv = acc[c][r] * scale;
      size_t idx = (size_t)(orow + r) * Nn + ocol + c * 16;
      if (OUT_F32) ((float*)Cout)[idx] = vv;
      else         ((u16*)Cout)[idx] = f2bf(vv);
    }
}

// ------------- 128x128-tile GEMM, global_load_lds + XOR swizzle (QKV proj) -------------
__global__ __launch_bounds__(256) void gemm128(const u16* __restrict__ A,
                                               const u16* __restrict__ Bt,
                                               u16* __restrict__ Cout,
                                               int Nn, int K, int Nq, float qs) {
  __shared__ __align__(16) u16 As[128][64];
  __shared__ __align__(16) u16 Bs[128][64];
  int tid = threadIdx.x, lane = tid & 63, wid = tid >> 6;
  int l15 = lane & 15, lhi = lane >> 4;
  int n0 = blockIdx.x * 128, m0 = blockIdx.y * 128;
  int wr = wid >> 1, wc = wid & 1;
  float scale = (n0 < Nq) ? qs : 1.0f;
  f32x4 acc[4][4];
#pragma unroll
  for (int mi = 0; mi < 4; ++mi)
#pragma unroll
    for (int ni = 0; ni < 4; ++ni) acc[mi][ni] = f32x4{0.f, 0.f, 0.f, 0.f};
  int srow = lane >> 3;                       // row within 8-row group
  int scol = ((lane & 7) ^ srow) * 8;         // inverse-swizzled source column (u16)
  for (int k0 = 0; k0 < K; k0 += 64) {
    __syncthreads();
#pragma unroll
    for (int i = 0; i < 4; ++i) {
      int row0 = wid * 32 + i * 8;
      gload_lds16(A + (size_t)(m0 + row0 + srow) * K + k0 + scol, &As[row0][0]);
      gload_lds16(Bt + (size_t)(n0 + row0 + srow) * K + k0 + scol, &Bs[row0][0]);
    }
    __syncthreads();   // compiler drains vmcnt(0) before s_barrier
#pragma unroll
    for (int ks = 0; ks < 2; ++ks) {
      s16x8 af[4], bf[4];
#pragma unroll
      for (int mi = 0; mi < 4; ++mi) {
        int row = wr * 64 + mi * 16 + l15;
        int c8 = (ks * 4 + lhi) ^ (row & 7);
        af[mi] = *(const s16x8*)&As[row][c8 * 8];
      }
#pragma unroll
      for (int ni = 0; ni < 4; ++ni) {
        int row = wc * 64 + ni * 16 + l15;
        int c8 = (ks * 4 + lhi) ^ (row & 7);
        bf[ni] = *(const s16x8*)&Bs[row][c8 * 8];
      }
#pragma unroll
      for (int mi = 0; mi < 4; ++mi)
#pragma unroll
        for (int ni = 0; ni < 4; ++ni)
          acc[mi][ni] = MFMA16(af[mi], bf[ni], acc[mi][ni]);
    }
  }
  int orow0 = m0 + wr * 64, ocol0 = n0 + wc * 64;
#pragma unroll
  for (int mi = 0; mi < 4; ++mi)
#pragma unroll
    for (int ni = 0; ni < 4; ++ni)
#pragma unroll
      for (int r = 0; r < 4; ++r) {
        int row = orow0 + mi * 16 + lhi * 4 + r;
        int col = ocol0 + ni * 16 + l15;
        Cout[(size_t)row * Nn + col] = f2bf(acc[mi][ni][r] * scale);
      }
}

// ------------- rows[(q,h)-view][64] @ Wt[64][64]^T + bias (+f32 add), bf16 out -------------
template<bool ADD>
__global__ __launch_bounds__(256) void small_gemm(
    const u16* __restrict__ A, int ldo, const u16* __restrict__ Wt,
    const float* __restrict__ bias, const float* __restrict__ addsrc,
    u16* __restrict__ outp) {
  __shared__ __align__(16) u16 Ws[64][72];
  int tid = threadIdx.x, lane = tid & 63, wid = tid >> 6;
  int l15 = lane & 15, lhi = lane >> 4;
  int m0 = blockIdx.x * 64;
  {
    int r = tid >> 2, cc = (tid & 3) * 8;
    *(s16x8*)&Ws[r][cc] = *(const s16x8*)(Wt + r * 64 + cc);
    *(s16x8*)&Ws[r][cc + 32] = *(const s16x8*)(Wt + r * 64 + cc + 32);
  }
  __syncthreads();
  int R = m0 + wid * 16 + l15;
  const u16* arow = A + (size_t)(R >> 4) * ldo + (R & 15) * 64;
  s16x8 a0 = *(const s16x8*)(arow + lhi * 8);
  s16x8 a1 = *(const s16x8*)(arow + 32 + lhi * 8);
  f32x4 acc[4];
#pragma unroll
  for (int c = 0; c < 4; ++c) {
    acc[c] = f32x4{0.f, 0.f, 0.f, 0.f};
    s16x8 b0 = *(const s16x8*)&Ws[c * 16 + l15][lhi * 8];
    s16x8 b1 = *(const s16x8*)&Ws[c * 16 + l15][32 + lhi * 8];
    acc[c] = MFMA16(a0, b0, acc[c]);
    acc[c] = MFMA16(a1, b1, acc[c]);
  }
  int orow = m0 + wid * 16 + lhi * 4;
#pragma unroll
  for (int c = 0; c < 4; ++c)
#pragma unroll
    for (int r = 0; r < 4; ++r) {
      int col = c * 16 + l15;
      size_t idx = (size_t)(orow + r) * 64 + col;
      float v = acc[c][r] + bias[col];
      if (ADD) v += addsrc[idx];
      outp[idx] = f2bf(v);
    }
}

// ======================= fused attention: stats + PV + GCN0 + deg + mask ===============
// One block per (head, 16-q strip); 4 waves split the causal chunk range.
template<bool STORE_ADJ>
__global__ __launch_bounds__(256) void attn_pv(
    const u16* __restrict__ QKV, const u16* __restrict__ Kp,
    const u16* __restrict__ Vp, const u16* __restrict__ H0p,
    float* __restrict__ mbuf, float* __restrict__ lbuf, float* __restrict__ degb,
    float* __restrict__ oatt, u16* __restrict__ g1,
    u16* __restrict__ adjS, unsigned char* __restrict__ maskb) {
  int tid = threadIdx.x, wq = tid >> 6, lane = tid & 63;
  int l15 = lane & 15, lhi = lane >> 4;
  int bid = blockIdx.x;
  int h = bid & 15, sidx = bid >> 4;
  int strip = 127 - sidx;                 // heavy strips dispatch first
  int qbase = strip * 16, q = qbase + l15, qmax = qbase + 15;
  int nch = (strip >> 2) + 1;
  int c_lo = (nch * wq) >> 2, c_hi = (nch * (wq + 1)) >> 2;
  int cumb = cumch(strip);

  __shared__ __align__(16) u16 pls[4][16][72];
  __shared__ __align__(16) u16 als[4][16][72];
  __shared__ float smf[4][16], slf[4][16], sdf[4][16];
  __shared__ float comb[3][4][64][4];
  u16 (*pbuf)[72] = pls[wq];
  u16 (*abuf)[72] = als[wq];

  const u16* qrow = QKV + (size_t)q * QKVLD + h * HD;
  s16x8 qf0 = *(const s16x8*)(qrow + lhi * 8);
  s16x8 qf1 = *(const s16x8*)(qrow + 32 + lhi * 8);
  const u16* KpH = Kp + (size_t)h * 128 * 1024;
  const float NEGB = -3.0e38f;

  // ---- phase 1: softmax stats over this wave's chunk range ----
  float mp = NEGB, lp = 0.f;
  for (int c0 = c_lo; c0 < c_hi; ++c0) {
    int j0 = c0 * 64;
    int vst = min(4, ((qmax - j0) >> 4) + 1);
    float sv[16], vmax = NEGB;
#pragma unroll
    for (int st = 0; st < 4; ++st) {
      if (st < vst) {
        int jb = j0 + st * 16;
        const u16* kb = KpH + (size_t)((j0 >> 4) + st) * 1024;
        s16x8 kf0 = *(const s16x8*)(kb + lane * 8);
        s16x8 kf1 = *(const s16x8*)(kb + 512 + lane * 8);
        f32x4 s = f32x4{0.f, 0.f, 0.f, 0.f};
        s = MFMA16(kf0, qf0, s);
        s = MFMA16(kf1, qf1, s);
#pragma unroll
        for (int r = 0; r < 4; ++r) {
          int j = jb + lhi * 4 + r;
          float v = (j <= q) ? s[r] : NEGB;
          sv[st * 4 + r] = v;
          vmax = fmaxf(vmax, v);
        }
      }
    }
    float mn = fmaxf(mp, vmax);
    float es = 0.f;
#pragma unroll
    for (int st = 0; st < 4; ++st) {
      if (st < vst) {
#pragma unroll
        for (int r = 0; r < 4; ++r) es += __expf(sv[st * 4 + r] - mn);
      }
    }
    lp = lp * __expf(mp - mn) + es;
    mp = mn;
  }
  // reduce across the 4 lhi lanes sharing q
#pragma unroll
  for (int off = 16; off <= 32; off <<= 1) {
    float mo = __shfl_xor(mp, off), lo = __shfl_xor(lp, off);
    float mn = fmaxf(mp, mo);
    lp = lp * __expf(mp - mn) + lo * __expf(mo - mn);
    mp = mn;
  }
  // block combine across 4 waves
  if (lhi == 0) { smf[wq][l15] = mp; slf[wq][l15] = lp; }
  __syncthreads();
  float m0_ = smf[0][l15], m1_ = smf[1][l15], m2_ = smf[2][l15], m3_ = smf[3][l15];
  float mt = fmaxf(fmaxf(m0_, m1_), fmaxf(m2_, m3_));
  float lt = slf[0][l15] * __expf(m0_ - mt) + slf[1][l15] * __expf(m1_ - mt) +
             slf[2][l15] * __expf(m2_ - mt) + slf[3][l15] * __expf(m3_ - mt);
  if (wq == 0 && lhi == 0) {
    mbuf[(size_t)h * SEQ + q] = mt;
    lbuf[(size_t)h * SEQ + q] = lt;
  }
  float invl = 1.0f / lt;

  // ---- phase 2: P@V, adj@h0, deg, mask over this wave's chunk range ----
  f32x4 pv[4], gc[4];
#pragma unroll
  for (int c = 0; c < 4; ++c) { pv[c] = f32x4{0.f,0.f,0.f,0.f}; gc[c] = f32x4{0.f,0.f,0.f,0.f}; }
  float dacc = 0.f;
  for (int c0 = c_lo; c0 < c_hi; ++c0) {
    int j0 = c0 * 64;
    int vst = min(4, ((qmax - j0) >> 4) + 1);
    int jc0 = j0 >> 5;
    bool kk1v = (vst > 2);
    // stage V fragments early (hidden under exp/threshold chain)
    const u16* vb0 = Vp + (size_t)(h * 64 + jc0) * 2048;
    s16x8 av0[4], av1[4];
#pragma unroll
    for (int c2 = 0; c2 < 4; ++c2) av0[c2] = *(const s16x8*)(vb0 + c2 * 512 + lane * 8);
    if (kk1v) {
#pragma unroll
      for (int c2 = 0; c2 < 4; ++c2) av1[c2] = *(const s16x8*)(vb0 + 2048 + c2 * 512 + lane * 8);
    }
    unsigned flags = 0;
#pragma unroll
    for (int st = 0; st < 4; ++st) {
      if (st < vst) {
        int jb = j0 + st * 16;
        const u16* kb = KpH + (size_t)((j0 >> 4) + st) * 1024;
        s16x8 kf0 = *(const s16x8*)(kb + lane * 8);
        s16x8 kf1 = *(const s16x8*)(kb + 512 + lane * 8);
        f32x4 s = f32x4{0.f, 0.f, 0.f, 0.f};
        s = MFMA16(kf0, qf0, s);
        s = MFMA16(kf1, qf1, s);
        float pr[4], ar[4], asum = 0.f;
#pragma unroll
        for (int r = 0; r < 4; ++r) {
          int j = jb + lhi * 4 + r;
          float p = (j <= q) ? __expf(s[r] - mt) * invl : 0.f;
          float a = (j == q) ? 1.f : ((p < 0.01f) ? 0.f : ((p > 0.9f) ? 1.f : p));
          dacc += a; asum += a;
          pr[r] = p; ar[r] = a;
        }
        ushort4 pu; pu.x = f2bf(pr[0]); pu.y = f2bf(pr[1]); pu.z = f2bf(pr[2]); pu.w = f2bf(pr[3]);
        *(ushort4*)&pbuf[l15][st * 16 + lhi * 4] = pu;
        unsigned long long bal = __ballot(asum > 0.f);
        if (bal) {
          flags |= 1u << (st >> 1);
          ushort4 au; au.x = f2bf(ar[0]); au.y = f2bf(ar[1]); au.z = f2bf(ar[2]); au.w = f2bf(ar[3]);
          *(ushort4*)&abuf[l15][st * 16 + lhi * 4] = au;
        } else {
          ushort4 z; z.x = 0; z.y = 0; z.z = 0; z.w = 0;
          *(ushort4*)&abuf[l15][st * 16 + lhi * 4] = z;
        }
      } else {
        ushort4 z; z.x = 0; z.y = 0; z.z = 0; z.w = 0;
        *(ushort4*)&pbuf[l15][st * 16 + lhi * 4] = z;
        *(ushort4*)&abuf[l15][st * 16 + lhi * 4] = z;
      }
    }
    if (lane == 0) maskb[(size_t)h * TOTCH + cumb + c0] = (unsigned char)flags;
    WAVE_LDS_FENCE();
    // kk = 0
    {
      s16x8 bp = *(const s16x8*)&pbuf[l15][lhi * 8];
#pragma unroll
      for (int c2 = 0; c2 < 4; ++c2) pv[c2] = MFMA16(av0[c2], bp, pv[c2]);
      if (flags & 1u) {
        s16x8 ba = *(const s16x8*)&abuf[l15][lhi * 8];
        if (STORE_ADJ)
          *(s16x8*)(adjS + ((size_t)(h * TOTCH + cumb + c0) * 2) * 512 + lane * 8) = ba;
        const u16* hb = H0p + (size_t)(h * 64 + jc0) * 2048;
#pragma unroll
        for (int c2 = 0; c2 < 4; ++c2) {
          s16x8 ah = *(const s16x8*)(hb + c2 * 512 + lane * 8);
          gc[c2] = MFMA16(ah, ba, gc[c2]);
        }
      }
    }
    // kk = 1
    if (kk1v) {
      s16x8 bp = *(const s16x8*)&pbuf[l15][32 + lhi * 8];
#pragma unroll
      for (int c2 = 0; c2 < 4; ++c2) pv[c2] = MFMA16(av1[c2], bp, pv[c2]);
      if (flags & 2u) {
        s16x8 ba = *(const s16x8*)&abuf[l15][32 + lhi * 8];
        if (STORE_ADJ)
          *(s16x8*)(adjS + ((size_t)(h * TOTCH + cumb + c0) * 2 + 1) * 512 + lane * 8) = ba;
        const u16* hb = H0p + (size_t)(h * 64 + jc0 + 1) * 2048;
#pragma unroll
        for (int c2 = 0; c2 < 4; ++c2) {
          s16x8 ah = *(const s16x8*)(hb + c2 * 512 + lane * 8);
          gc[c2] = MFMA16(ah, ba, gc[c2]);
        }
      }
    }
  }
  // deg partial
  dacc += __shfl_xor(dacc, 16);
  dacc += __shfl_xor(dacc, 32);
  if (lhi == 0) sdf[wq][l15] = dacc;
  // combine pv
  if (wq > 0) {
#pragma unroll
    for (int c2 = 0; c2 < 4; ++c2) *(f32x4*)&comb[wq - 1][c2][lane][0] = pv[c2];
  }
  __syncthreads();
  if (wq == 0) {
#pragma unroll
    for (int c2 = 0; c2 < 4; ++c2)
      pv[c2] += *(const f32x4*)&comb[0][c2][lane][0] +
                *(const f32x4*)&comb[1][c2][lane][0] +
                *(const f32x4*)&comb[2][c2][lane][0];
  }
  __syncthreads();
  if (wq > 0) {
#pragma unroll
    for (int c2 = 0; c2 < 4; ++c2) *(f32x4*)&comb[wq - 1][c2][lane][0] = gc[c2];
  }
  __syncthreads();
  if (wq == 0) {
    float dtot = sdf[0][l15] + sdf[1][l15] + sdf[2][l15] + sdf[3][l15];
    if (lhi == 0) degb[(size_t)h * SEQ + q] = dtot;
    float dinv = 1.0f / dtot;
    const u16* Vrows = QKV + 2048 + (size_t)h * HD;
#pragma unroll
    for (int c2 = 0; c2 < 4; ++c2) {
      f32x4 gct = gc[c2] + *(const f32x4*)&comb[0][c2][lane][0] +
                  *(const f32x4*)&comb[1][c2][lane][0] +
                  *(const f32x4*)&comb[2][c2][lane][0];
      *(f32x4*)&oatt[(size_t)q * DIM + h * HD + c2 * 16 + lhi * 4] = pv[c2];
      ushort4 vv = *(const ushort4*)(Vrows + (size_t)q * QKVLD + c2 * 16 + lhi * 4);
      ushort4 o;
      o.x = f2bf(gelu_exact(gct[0] * dinv + bf2f(vv.x)));
      o.y = f2bf(gelu_exact(gct[1] * dinv + bf2f(vv.y)));
      o.z = f2bf(gelu_exact(gct[2] * dinv + bf2f(vv.z)));
      o.w = f2bf(gelu_exact(gct[3] * dinv + bf2f(vv.w)));
      *(ushort4*)&g1[(size_t)q * DIM + h * HD + c2 * 16 + lhi * 4] = o;
    }
  }
}

// ======================= GCN layer 1: g2 = gelu(adj@h1/deg + g1), mask-gated ============
template<bool READ_ADJ>
__global__ __launch_bounds__(256) void attn_gcn1(
    const u16* __restrict__ QKV, const u16* __restrict__ Kp,
    const u16* __restrict__ H1p, const u16* __restrict__ adjS,
    const unsigned char* __restrict__ maskb,
    const float* __restrict__ mbuf, const float* __restrict__ lbuf,
    const float* __restrict__ degb,
    const u16* __restrict__ g1, u16* __restrict__ g2) {
  int tid = threadIdx.x, wq = tid >> 6, lane = tid & 63;
  int l15 = lane & 15, lhi = lane >> 4;
  int bid = blockIdx.x;
  int h = bid & 15, sidx = bid >> 4;
  int strip = 127 - sidx;
  int qbase = strip * 16, q = qbase + l15, qmax = qbase + 15;
  int nch = (strip >> 2) + 1;
  int c_lo = (nch * wq) >> 2, c_hi = (nch * (wq + 1)) >> 2;
  int cumb = cumch(strip);

  __shared__ float comb[3][4][64][4];

  f32x4 gc[4];
#pragma unroll
  for (int c = 0; c < 4; ++c) gc[c] = f32x4{0.f, 0.f, 0.f, 0.f};

  if constexpr (READ_ADJ) {
    for (int c0 = c_lo; c0 < c_hi; ++c0) {
      unsigned flags = maskb[(size_t)h * TOTCH + cumb + c0];
      if (!flags) continue;
      int jc0 = (c0 * 64) >> 5;
#pragma unroll
      for (int kk = 0; kk < 2; ++kk) {
        if (!((flags >> kk) & 1u)) continue;
        s16x8 ba = *(const s16x8*)(adjS + ((size_t)(h * TOTCH + cumb + c0) * 2 + kk) * 512 + lane * 8);
        const u16* hb = H1p + (size_t)(h * 64 + jc0 + kk) * 2048;
#pragma unroll
        for (int c2 = 0; c2 < 4; ++c2) {
          s16x8 ah = *(const s16x8*)(hb + c2 * 512 + lane * 8);
          gc[c2] = MFMA16(ah, ba, gc[c2]);
        }
      }
    }
  } else {
    __shared__ __align__(16) u16 als2[4][16][72];
    u16 (*abuf)[72] = als2[wq];
    const u16* qrow = QKV + (size_t)q * QKVLD + h * HD;
    s16x8 qf0 = *(const s16x8*)(qrow + lhi * 8);
    s16x8 qf1 = *(const s16x8*)(qrow + 32 + lhi * 8);
    const u16* KpH = Kp + (size_t)h * 128 * 1024;
    float mt = mbuf[(size_t)h * SEQ + q];
    float invl = 1.0f / lbuf[(size_t)h * SEQ + q];
    for (int c0 = c_lo; c0 < c_hi; ++c0) {
      unsigned flags = maskb[(size_t)h * TOTCH + cumb + c0];
      if (!flags) continue;
      int j0 = c0 * 64;
      int vst = min(4, ((qmax - j0) >> 4) + 1);
      int jc0 = j0 >> 5;
#pragma unroll
      for (int st = 0; st < 4; ++st) {
        if (st < vst) {
          int jb = j0 + st * 16;
          const u16* kb = KpH + (size_t)((j0 >> 4) + st) * 1024;
          s16x8 kf0 = *(const s16x8*)(kb + lane * 8);
          s16x8 kf1 = *(const s16x8*)(kb + 512 + lane * 8);
          f32x4 s = f32x4{0.f, 0.f, 0.f, 0.f};
          s = MFMA16(kf0, qf0, s);
          s = MFMA16(kf1, qf1, s);
          float ar[4];
#pragma unroll
          for (int r = 0; r < 4; ++r) {
            int j = jb + lhi * 4 + r;
            float p = (j <= q) ? __expf(s[r] - mt) * invl : 0.f;
            ar[r] = (j == q) ? 1.f : ((p < 0.01f) ? 0.f : ((p > 0.9f) ? 1.f : p));
          }
          ushort4 au; au.x = f2bf(ar[0]); au.y = f2bf(ar[1]); au.z = f2bf(ar[2]); au.w = f2bf(ar[3]);
          *(ushort4*)&abuf[l15][st * 16 + lhi * 4] = au;
        } else {
          ushort4 z; z.x = 0; z.y = 0; z.z = 0; z.w = 0;
          *(ushort4*)&abuf[l15][st * 16 + lhi * 4] = z;
        }
      }
      WAVE_LDS_FENCE();
#pragma unroll
      for (int kk = 0; kk < 2; ++kk) {
        if (!((flags >> kk) & 1u)) continue;
        s16x8 ba = *(const s16x8*)&abuf[l15][kk * 32 + lhi * 8];
        const u16* hb = H1p + (size_t)(h * 64 + jc0 + kk) * 2048;
#pragma unroll
        for (int c2 = 0; c2 < 4; ++c2) {
          s16x8 ah = *(const s16x8*)(hb + c2 * 512 + lane * 8);
          gc[c2] = MFMA16(ah, ba, gc[c2]);
        }
      }
      WAVE_LDS_FENCE();
    }
  }

  if (wq > 0) {
#pragma unroll
    for (int c2 = 0; c2 < 4; ++c2) *(f32x4*)&comb[wq - 1][c2][lane][0] = gc[c2];
  }
  __syncthreads();
  if (wq == 0) {
    float dinv = 1.0f / degb[(size_t)h * SEQ + q];
#pragma unroll
    for (int c2 = 0; c2 < 4; ++c2) {
      f32x4 gct = gc[c2] + *(const f32x4*)&comb[0][c2][lane][0] +
                  *(const f32x4*)&comb[1][c2][lane][0] +
                  *(const f32x4*)&comb[2][c2][lane][0];
      ushort4 sv = *(const ushort4*)(g1 + (size_t)q * DIM + h * HD + c2 * 16 + lhi * 4);
      ushort4 o;
      o.x = f2bf(gelu_exact(gct[0] * dinv + bf2f(sv.x)));
      o.y = f2bf(gelu_exact(gct[1] * dinv + bf2f(sv.y)));
      o.z = f2bf(gelu_exact(gct[2] * dinv + bf2f(sv.z)));
      o.w = f2bf(gelu_exact(gct[3] * dinv + bf2f(sv.w)));
      *(ushort4*)&g2[(size_t)q * DIM + h * HD + c2 * 16 + lhi * 4] = o;
    }
  }
}

extern "C" void kernel_launch(void* const* d_in, const int* in_sizes, int n_in,
                              void* d_out, int out_size, void* d_ws, size_t ws_size,
                              hipStream_t stream) {
  (void)in_sizes; (void)n_in; (void)out_size;
  const float* x       = (const float*)d_in[0];
  const float* gamma_n = (const float*)d_in[1];
  const float* Wq      = (const float*)d_in[2];
  const float* Wk      = (const float*)d_in[3];
  const float* Wv      = (const float*)d_in[4];
  const float* Wout    = (const float*)d_in[5];
  const float* gamma_o = (const float*)d_in[6];
  const float* Wg0     = (const float*)d_in[7];
  const float* bg0     = (const float*)d_in[8];
  const float* Wg1     = (const float*)d_in[9];
  const float* bg1     = (const float*)d_in[10];
  const float* Wlin    = (const float*)d_in[11];
  const float* blin    = (const float*)d_in[12];
  float* out = (float*)d_out;

  char* w = (char*)d_ws;
  size_t off = 0;
  auto alloc = [&](size_t bytes) -> void* {
    void* p = w + off;
    off = (off + bytes + 255) & ~(size_t)255;
    return p;
  };
  u16* xn      = (u16*)alloc((size_t)SEQ * DIM * 2);
  u16* WqkvT   = (u16*)alloc((size_t)3 * DIM * DIM * 2);
  u16* WoT     = (u16*)alloc((size_t)DIM * DIM * 2);
  u16* Wg0T    = (u16*)alloc(64 * 64 * 2);
  u16* Wg1T    = (u16*)alloc(64 * 64 * 2);
  u16* WlinT   = (u16*)alloc(64 * 64 * 2);
  u16* QKV     = (u16*)alloc((size_t)SEQ * QKVLD * 2);
  float* mbuf  = (float*)alloc((size_t)HEADS * SEQ * 4);
  float* lbuf  = (float*)alloc((size_t)HEADS * SEQ * 4);
  float* degb  = (float*)alloc((size_t)HEADS * SEQ * 4);
  float* oatt  = (float*)alloc((size_t)SEQ * DIM * 4);
  u16* h0      = (u16*)alloc((size_t)SEQ * DIM * 2);
  u16* g1      = (u16*)alloc((size_t)SEQ * DIM * 2);
  u16* h1      = (u16*)alloc((size_t)SEQ * DIM * 2);
  u16* g2      = (u16*)alloc((size_t)SEQ * DIM * 2);
  u16* Kp      = (u16*)alloc((size_t)HEADS * 128 * 1024 * 2);
  u16* Vp      = (u16*)alloc((size_t)HEADS * 64 * 4 * 512 * 2);
  u16* H0p     = (u16*)alloc((size_t)HEADS * 64 * 4 * 512 * 2);
  u16* H1p     = (u16*)alloc((size_t)HEADS * 64 * 4 * 512 * 2);
  u16* Om      = (u16*)alloc((size_t)SEQ * DIM * 2);
  unsigned char* maskb = (unsigned char*)alloc((size_t)HEADS * TOTCH);
  float* Y     = (float*)QKV;   // alias: QKV dead after attn_gcn1

  size_t adj_bytes = (size_t)HEADS * TOTCH * 2 * 512 * 2;   // worst-case causal-packed
  bool use_adj = (off + adj_bytes) <= ws_size;
  u16* adjS = use_adj ? (u16*)alloc(adj_bytes) : nullptr;

  // 1) LN(x) -> xn (bf16)
  ln_rows<true><<<SEQ, 256, 0, stream>>>(x, gamma_n, xn);
  // 2) weight transposes fp32->bf16 [N][K]
  transpose_convert<<<dim3(16, 16), 256, 0, stream>>>(Wq, WqkvT, DIM, DIM);
  transpose_convert<<<dim3(16, 16), 256, 0, stream>>>(Wk, WqkvT + (size_t)DIM * DIM, DIM, DIM);
  transpose_convert<<<dim3(16, 16), 256, 0, stream>>>(Wv, WqkvT + (size_t)2 * DIM * DIM, DIM, DIM);
  transpose_convert<<<dim3(16, 16), 256, 0, stream>>>(Wout, WoT, DIM, DIM);
  transpose_convert<<<dim3(1, 1), 256, 0, stream>>>(Wg0, Wg0T, 64, 64);
  transpose_convert<<<dim3(1, 1), 256, 0, stream>>>(Wg1, Wg1T, 64, 64);
  transpose_convert<<<dim3(1, 1), 256, 0, stream>>>(Wlin, WlinT, 64, 64);
  // 3) fused QKV projection, 128x128 tile (Q cols scaled by 0.125)
  gemm128<<<dim3(24, 16), 256, 0, stream>>>(xn, WqkvT, QKV, QKVLD, DIM, 1024, 0.125f);
  // 4) pack K fragments
  pack_k<<<512, 256, 0, stream>>>(QKV, Kp);
  // 5) h0 = V@Wg0 + b0
  small_gemm<false><<<512, 256, 0, stream>>>(QKV + 2048, QKVLD, Wg0T, bg0, nullptr, h0);
  // 6) pack V, h0 fragments
  pack_op<<<dim3(32, 16), 256, 0, stream>>>(QKV, QKVLD, 2048, Vp);
  pack_op<<<dim3(32, 16), 256, 0, stream>>>(h0, DIM, 0, H0p);
  // 7) fused attention (stats + P@V + adj@h0 + deg + mask [+ sparse adj store])
  if (use_adj)
    attn_pv<true><<<2048, 256, 0, stream>>>(QKV, Kp, Vp, H0p, mbuf, lbuf, degb, oatt, g1, adjS, maskb);
  else
    attn_pv<false><<<2048, 256, 0, stream>>>(QKV, Kp, Vp, H0p, mbuf, lbuf, degb, oatt, g1, nullptr, maskb);
  // 8) h1 = g1@Wg1 + b1
  small_gemm<false><<<512, 256, 0, stream>>>(g1, DIM, Wg1T, bg1, nullptr, h1);
  // 9) pack h1 fragments
  pack_op<<<dim3(32, 16), 256, 0, stream>>>(h1, DIM, 0, H1p);
  // 10) g2 = gelu(adj@h1/deg + g1)
  if (use_adj)
    attn_gcn1<true><<<2048, 256, 0, stream>>>(QKV, Kp, H1p, adjS, maskb, mbuf, lbuf, degb, g1, g2);
  else
    attn_gcn1<false><<<2048, 256, 0, stream>>>(QKV, Kp, H1p, nullptr, maskb, mbuf, lbuf, degb, g1, g2);
  // 11) Om = g2@Wlin + blin + oatt
  small_gemm<true><<<512, 256, 0, stream>>>(g2, DIM, WlinT, blin, oatt, Om);
  // 12) Y = Om @ Wout (f32)  [Y aliases QKV]
  gemm_bf16<true><<<dim3(16, 32), 256, 0, stream>>>(Om, WoT, Y, DIM, DIM, 0, 1.0f);
  // 13) LN(Y) -> out (f32)
  ln_rows<false><<<SEQ, 256, 0, stream>>>(Y, gamma_o, out);
}